// Round 1
// baseline (2232.298 us; speedup 1.0000x reference)
//
#include <hip/hip_runtime.h>
#include <hip/hip_bf16.h>
#include <math.h>

#define B_   2
#define T_   2048
#define C_   768
#define NH   12
#define HS   64
#define NSEG 16
#define SEGLEN 128

// ---------------- GEMM: C[m,n] = sum_k A[m,k] * B[n,k]  (NT gemm, W stored (out,in)) ----
__global__ __launch_bounds__(256) void gemm_nt_f32(const float* __restrict__ A,
                                                   const float* __restrict__ B,
                                                   float* __restrict__ C,
                                                   int M, int N, int K) {
  __shared__ float As[16][64];
  __shared__ float Bs[16][64];
  const int tid = threadIdx.x;
  const int bm = blockIdx.x * 64;
  const int bn = blockIdx.y * 64;
  const int tr = tid >> 4;        // 0..15
  const int tc = tid & 15;        // 0..15
  const int lr = tid >> 2;        // 0..63
  const int lc = (tid & 3) << 2;  // 0,4,8,12
  const float* Ap = A + (size_t)(bm + lr) * K + lc;
  const float* Bp = B + (size_t)(bn + lr) * K + lc;
  float acc[4][4] = {};
  for (int k0 = 0; k0 < K; k0 += 16) {
    float4 a4 = *(const float4*)(Ap + k0);
    float4 b4 = *(const float4*)(Bp + k0);
    __syncthreads();
    As[lc + 0][lr] = a4.x; As[lc + 1][lr] = a4.y; As[lc + 2][lr] = a4.z; As[lc + 3][lr] = a4.w;
    Bs[lc + 0][lr] = b4.x; Bs[lc + 1][lr] = b4.y; Bs[lc + 2][lr] = b4.z; Bs[lc + 3][lr] = b4.w;
    __syncthreads();
#pragma unroll
    for (int k = 0; k < 16; ++k) {
      float4 av = *(const float4*)&As[k][tr * 4];
      float4 bv = *(const float4*)&Bs[k][tc * 4];
      float a_[4] = {av.x, av.y, av.z, av.w};
      float b_[4] = {bv.x, bv.y, bv.z, bv.w};
#pragma unroll
      for (int i = 0; i < 4; ++i)
#pragma unroll
        for (int j = 0; j < 4; ++j) acc[i][j] = fmaf(a_[i], b_[j], acc[i][j]);
    }
  }
#pragma unroll
  for (int i = 0; i < 4; ++i) {
    float4 o = make_float4(acc[i][0], acc[i][1], acc[i][2], acc[i][3]);
    *(float4*)(C + (size_t)(bm + tr * 4 + i) * N + bn + tc * 4) = o;
  }
}

// ---------------- Scan pass A: local (zero-init) leaky-average per segment ----------
// u layout: (B*T, C).  kbuf layout: (B, NH, T, HS).
__global__ __launch_bounds__(256) void scan_a(const float* __restrict__ u,
                                              const float* __restrict__ la_coef,
                                              float* __restrict__ kbuf,
                                              float* __restrict__ segend) {
  int cid = blockIdx.x * 4 + (threadIdx.x >> 6);  // (bh, seg)
  int d   = threadIdx.x & 63;
  int seg = cid & (NSEG - 1);
  int bh  = cid >> 4;
  int h   = bh % NH;
  int b   = bh / NH;
  float c  = la_coef[h];
  float oc = 1.f - c;
  int t0 = seg * SEGLEN;
  const float* up = u + ((size_t)b * T_ + t0) * C_ + h * HS + d;
  float* kp = kbuf + ((size_t)bh * T_ + t0) * HS + d;
  float y = 0.f;
  for (int i = 0; i < SEGLEN; ++i) {
    float uv = up[(size_t)i * C_];
    y = fmaf(c, y, oc * uv);
    kp[(size_t)i * HS] = y;
  }
  segend[(size_t)cid * HS + d] = y;
}

// ---------------- Scan pass B: sequential combine of 16 segment carries -------------
__global__ __launch_bounds__(256) void scan_b(const float* __restrict__ la_coef,
                                              const float* __restrict__ segend,
                                              float* __restrict__ carryin) {
  int s = blockIdx.x * 256 + threadIdx.x;  // (b,h,d)
  if (s >= B_ * NH * HS) return;
  int d  = s & 63;
  int bh = s >> 6;
  int h  = bh % NH;
  float c = la_coef[h];
  float cl = c;
#pragma unroll
  for (int i = 0; i < 7; ++i) cl *= cl;  // c^128
  float h0 = 0.f;
  for (int seg = 0; seg < NSEG; ++seg) {
    int cid = bh * NSEG + seg;
    carryin[(size_t)cid * HS + d] = h0;
    h0 = fmaf(cl, h0, segend[(size_t)cid * HS + d]);
  }
}

// ---------------- Scan pass C + k normalization (fused) -----------------------------
__global__ __launch_bounds__(256) void scan_c_norm(const float* __restrict__ la_coef,
                                                   const float* __restrict__ kernel_beta,
                                                   const float* __restrict__ carryin,
                                                   float* __restrict__ kbuf) {
  int cid = blockIdx.x * 4 + (threadIdx.x >> 6);
  int d   = threadIdx.x & 63;
  int seg = cid & (NSEG - 1);
  int bh  = cid >> 4;
  int h   = bh % NH;
  float c  = la_coef[h];
  float bk = __expf(fminf(kernel_beta[h] * 10.f, 5.f));
  float hin = carryin[(size_t)cid * HS + d];
  int t0 = seg * SEGLEN;
  float* kp = kbuf + ((size_t)bh * T_ + t0) * HS + d;
  float powc = c;
  for (int i = 0; i < SEGLEN; ++i) {
    float val = fmaf(powc, hin, kp[(size_t)i * HS]);
    powc *= c;
    float ss = val * val;
#pragma unroll
    for (int off = 1; off < 64; off <<= 1) ss += __shfl_xor(ss, off, 64);
    float scale = bk / (sqrtf(ss) + 1e-6f);
    kp[(size_t)i * HS] = val * scale;
  }
}

// ---------------- v build: shift-mix, normalize, scale -------------------------------
// xv layout (B*T, C); vbuf layout (B, NH, T, HS)
__global__ __launch_bounds__(256) void vbuild(const float* __restrict__ xv,
                                              const float* __restrict__ v_coef,
                                              const float* __restrict__ value_beta,
                                              float* __restrict__ vbuf) {
  int row = blockIdx.x * 4 + (threadIdx.x >> 6);  // bh*T + t
  int d   = threadIdx.x & 63;
  int t   = row & (T_ - 1);
  int bh  = row / T_;
  int h   = bh % NH;
  int b   = bh / NH;
  float vc = v_coef[h];
  float vb = __expf(fminf(value_beta[h] * 10.f, 5.f));
  const float* xp = xv + ((size_t)b * T_ + t) * C_ + h * HS + d;
  float x0 = *xp;
  float x1 = (t + 1 < T_) ? xp[C_] : 0.f;
  float vf = (1.f - vc) * x1 + vc * x0;
  float ss = vf * vf;
#pragma unroll
  for (int off = 1; off < 64; off <<= 1) ss += __shfl_xor(ss, off, 64);
  float scale = vb / (sqrtf(ss) + 1e-6f);
  vbuf[(size_t)row * HS + d] = vf * scale;
}

// ---------------- zero y rows at t=0 -------------------------------------------------
__global__ void yzero(float* __restrict__ y) {
  int i = blockIdx.x * 256 + threadIdx.x;
  if (i < B_ * C_) {
    int b = i / C_, c = i % C_;
    y[(size_t)b * T_ * C_ + c] = 0.f;
  }
}

// ---------------- causal attention, fixed-shift softmax, key-split across 4 waves ----
// Kb/Vb layout (B,NH,T,HS); Y layout (B,T,C). Query tq uses k-row tq, attends keys j<tq.
__global__ __launch_bounds__(256) void attn_f32(const float* __restrict__ Kb,
                                                const float* __restrict__ Vb,
                                                const float* __restrict__ kernel_beta,
                                                float* __restrict__ Y) {
  __shared__ float red[64][65];
  __shared__ float lred[4][64];
  int qb = blockIdx.x;
  int bh = blockIdx.y;
  int b = bh / NH, h = bh % NH;
  int w = threadIdx.x >> 6, lane = threadIdx.x & 63;
  int qs = 1 + qb * 64;
  int tq = qs + lane;
  bool active = tq < T_;
  const float* Kh = Kb + (size_t)bh * T_ * HS;
  const float* Vh = Vb + (size_t)bh * T_ * HS;
  float bk = __expf(fminf(kernel_beta[h] * 10.f, 5.f));
  float m0 = bk * bk;  // fixed softmax shift: scores bounded by bk^2

  float4 q[16];
  {
    const float4* qp = (const float4*)(Kh + (size_t)(active ? tq : 0) * HS);
#pragma unroll
    for (int i = 0; i < 16; ++i) q[i] = qp[i];
  }
  float4 acc[16];
#pragma unroll
  for (int i = 0; i < 16; ++i) acc[i] = make_float4(0.f, 0.f, 0.f, 0.f);
  float l = 0.f;

  int NT = qb + 1;  // key tiles 0..qb
  for (int kt = w; kt < NT; kt += 4) {
    int j0 = kt * 64;
#pragma unroll 2
    for (int j = 0; j < 64; ++j) {
      int jj = j0 + j;
      const float4* kr = (const float4*)(Kh + (size_t)jj * HS);
      float s = 0.f;
#pragma unroll
      for (int i = 0; i < 16; ++i) {
        float4 kv = kr[i];
        s = fmaf(q[i].x, kv.x, fmaf(q[i].y, kv.y, fmaf(q[i].z, kv.z, fmaf(q[i].w, kv.w, s))));
      }
      float p = (active && jj < tq) ? __expf(s - m0) : 0.f;
      l += p;
      const float4* vr = (const float4*)(Vh + (size_t)jj * HS);
#pragma unroll
      for (int i = 0; i < 16; ++i) {
        float4 vv = vr[i];
        acc[i].x = fmaf(p, vv.x, acc[i].x);
        acc[i].y = fmaf(p, vv.y, acc[i].y);
        acc[i].z = fmaf(p, vv.z, acc[i].z);
        acc[i].w = fmaf(p, vv.w, acc[i].w);
      }
    }
  }

  lred[w][lane] = l;
  for (int r = 1; r < 4; ++r) {
    __syncthreads();
    if (w == r) {
#pragma unroll
      for (int i = 0; i < 16; ++i) {
        red[lane][i * 4 + 0] = acc[i].x; red[lane][i * 4 + 1] = acc[i].y;
        red[lane][i * 4 + 2] = acc[i].z; red[lane][i * 4 + 3] = acc[i].w;
      }
    }
    __syncthreads();
    if (w == 0) {
#pragma unroll
      for (int i = 0; i < 16; ++i) {
        acc[i].x += red[lane][i * 4 + 0]; acc[i].y += red[lane][i * 4 + 1];
        acc[i].z += red[lane][i * 4 + 2]; acc[i].w += red[lane][i * 4 + 3];
      }
    }
  }
  if (w == 0 && active) {
    float ltot = lred[0][lane] + lred[1][lane] + lred[2][lane] + lred[3][lane];
    float inv = 1.f / ltot;
    float* yp = Y + ((size_t)b * T_ + tq) * C_ + h * HS;
#pragma unroll
    for (int i = 0; i < 16; ++i) {
      float4 o = make_float4(acc[i].x * inv, acc[i].y * inv, acc[i].z * inv, acc[i].w * inv);
      *(float4*)(yp + i * 4) = o;
    }
  }
}

extern "C" void kernel_launch(void* const* d_in, const int* in_sizes, int n_in,
                              void* d_out, int out_size, void* d_ws, size_t ws_size,
                              hipStream_t stream) {
  const float* x          = (const float*)d_in[0];
  const float* W_la       = (const float*)d_in[1];
  const float* la_coef    = (const float*)d_in[2];
  const float* W_v        = (const float*)d_in[3];
  const float* v_coef     = (const float*)d_in[4];
  const float* kernel_bet = (const float*)d_in[5];
  const float* value_bet  = (const float*)d_in[6];
  const float* W_proj     = (const float*)d_in[7];
  float* out = (float*)d_out;

  float* ws = (float*)d_ws;
  const size_t NTOK = (size_t)B_ * T_ * C_;  // 3,145,728
  float* u    = ws;              // (B*T, C)  — reused as y after scan consumes it
  float* xv   = u + NTOK;        // (B*T, C)
  float* kbuf = xv + NTOK;       // (B,NH,T,HS)
  float* vbuf = kbuf + NTOK;     // (B,NH,T,HS)
  float* segend  = vbuf + NTOK;            // 24576
  float* carryin = segend + (size_t)B_ * NH * NSEG * HS;  // 24576
  float* ybuf = u;               // alias: u dead after scan_a

  const int M = B_ * T_;  // 4096

  // u = x @ W_la^T ; xv = x @ W_v^T
  dim3 ggrid(M / 64, C_ / 64);
  gemm_nt_f32<<<ggrid, 256, 0, stream>>>(x, W_la, u, M, C_, C_);
  gemm_nt_f32<<<ggrid, 256, 0, stream>>>(x, W_v, xv, M, C_, C_);

  // leaky-average scan -> kbuf (local), then combine + normalize
  scan_a<<<dim3(B_ * NH * NSEG / 4), 256, 0, stream>>>(u, la_coef, kbuf, segend);
  scan_b<<<dim3((B_ * NH * HS + 255) / 256), 256, 0, stream>>>(la_coef, segend, carryin);
  scan_c_norm<<<dim3(B_ * NH * NSEG / 4), 256, 0, stream>>>(la_coef, kernel_bet, carryin, kbuf);

  // v path
  vbuild<<<dim3(B_ * NH * T_ / 4), 256, 0, stream>>>(xv, v_coef, value_bet, vbuf);

  // y (aliased onto u): zero t=0 rows, attention fills t=1..T-1
  yzero<<<dim3((B_ * C_ + 255) / 256), 256, 0, stream>>>(ybuf);
  attn_f32<<<dim3(T_ / 64, B_ * NH), 256, 0, stream>>>(kbuf, vbuf, kernel_bet, ybuf);

  // out = y @ W_proj^T
  gemm_nt_f32<<<ggrid, 256, 0, stream>>>(ybuf, W_proj, out, M, C_, C_);
}

// Round 2
// 362.489 us; speedup vs baseline: 6.1582x; 6.1582x over previous
//
#include <hip/hip_runtime.h>
#include <hip/hip_bf16.h>
#include <math.h>

#define B_   2
#define T_   2048
#define C_   768
#define NH   12
#define HS   64
#define NSEG 16
#define SEGLEN 128

typedef __attribute__((ext_vector_type(8))) short short8;
typedef __attribute__((ext_vector_type(4))) float f32x4;

// ---------------- GEMM: C[m,n] = sum_k A[m,k] * B[n,k]  (NT gemm, W stored (out,in)) ----
__global__ __launch_bounds__(256) void gemm_nt_f32(const float* __restrict__ A,
                                                   const float* __restrict__ B,
                                                   float* __restrict__ C,
                                                   int M, int N, int K) {
  __shared__ float As[16][64];
  __shared__ float Bs[16][64];
  const int tid = threadIdx.x;
  const int bm = blockIdx.x * 64;
  const int bn = blockIdx.y * 64;
  const int tr = tid >> 4;        // 0..15
  const int tc = tid & 15;        // 0..15
  const int lr = tid >> 2;        // 0..63
  const int lc = (tid & 3) << 2;  // 0,4,8,12
  const float* Ap = A + (size_t)(bm + lr) * K + lc;
  const float* Bp = B + (size_t)(bn + lr) * K + lc;
  float acc[4][4] = {};
  for (int k0 = 0; k0 < K; k0 += 16) {
    float4 a4 = *(const float4*)(Ap + k0);
    float4 b4 = *(const float4*)(Bp + k0);
    __syncthreads();
    As[lc + 0][lr] = a4.x; As[lc + 1][lr] = a4.y; As[lc + 2][lr] = a4.z; As[lc + 3][lr] = a4.w;
    Bs[lc + 0][lr] = b4.x; Bs[lc + 1][lr] = b4.y; Bs[lc + 2][lr] = b4.z; Bs[lc + 3][lr] = b4.w;
    __syncthreads();
#pragma unroll
    for (int k = 0; k < 16; ++k) {
      float4 av = *(const float4*)&As[k][tr * 4];
      float4 bv = *(const float4*)&Bs[k][tc * 4];
      float a_[4] = {av.x, av.y, av.z, av.w};
      float b_[4] = {bv.x, bv.y, bv.z, bv.w};
#pragma unroll
      for (int i = 0; i < 4; ++i)
#pragma unroll
        for (int j = 0; j < 4; ++j) acc[i][j] = fmaf(a_[i], b_[j], acc[i][j]);
    }
  }
#pragma unroll
  for (int i = 0; i < 4; ++i) {
    float4 o = make_float4(acc[i][0], acc[i][1], acc[i][2], acc[i][3]);
    *(float4*)(C + (size_t)(bm + tr * 4 + i) * N + bn + tc * 4) = o;
  }
}

// ---------------- Scan pass A: local (zero-init) leaky-average per segment ----------
__global__ __launch_bounds__(256) void scan_a(const float* __restrict__ u,
                                              const float* __restrict__ la_coef,
                                              float* __restrict__ kbuf,
                                              float* __restrict__ segend) {
  int cid = blockIdx.x * 4 + (threadIdx.x >> 6);  // (bh, seg)
  int d   = threadIdx.x & 63;
  int seg = cid & (NSEG - 1);
  int bh  = cid >> 4;
  int h   = bh % NH;
  int b   = bh / NH;
  float c  = la_coef[h];
  float oc = 1.f - c;
  int t0 = seg * SEGLEN;
  const float* up = u + ((size_t)b * T_ + t0) * C_ + h * HS + d;
  float* kp = kbuf + ((size_t)bh * T_ + t0) * HS + d;
  float y = 0.f;
  for (int i = 0; i < SEGLEN; ++i) {
    float uv = up[(size_t)i * C_];
    y = fmaf(c, y, oc * uv);
    kp[(size_t)i * HS] = y;
  }
  segend[(size_t)cid * HS + d] = y;
}

// ---------------- Scan pass B: sequential combine of 16 segment carries -------------
__global__ __launch_bounds__(256) void scan_b(const float* __restrict__ la_coef,
                                              const float* __restrict__ segend,
                                              float* __restrict__ carryin) {
  int s = blockIdx.x * 256 + threadIdx.x;  // (b,h,d)
  if (s >= B_ * NH * HS) return;
  int d  = s & 63;
  int bh = s >> 6;
  int h  = bh % NH;
  float c = la_coef[h];
  float cl = c;
#pragma unroll
  for (int i = 0; i < 7; ++i) cl *= cl;  // c^128
  float h0 = 0.f;
  for (int seg = 0; seg < NSEG; ++seg) {
    int cid = bh * NSEG + seg;
    carryin[(size_t)cid * HS + d] = h0;
    h0 = fmaf(cl, h0, segend[(size_t)cid * HS + d]);
  }
}

// ---------------- Scan pass C + k normalization, writes bf16 ------------------------
__global__ __launch_bounds__(256) void scan_c_norm(const float* __restrict__ la_coef,
                                                   const float* __restrict__ kernel_beta,
                                                   const float* __restrict__ carryin,
                                                   const float* __restrict__ kbuf,
                                                   __hip_bfloat16* __restrict__ kb16) {
  int cid = blockIdx.x * 4 + (threadIdx.x >> 6);
  int d   = threadIdx.x & 63;
  int seg = cid & (NSEG - 1);
  int bh  = cid >> 4;
  int h   = bh % NH;
  float c  = la_coef[h];
  float bk = __expf(fminf(kernel_beta[h] * 10.f, 5.f));
  float hin = carryin[(size_t)cid * HS + d];
  int t0 = seg * SEGLEN;
  const float* kp = kbuf + ((size_t)bh * T_ + t0) * HS + d;
  __hip_bfloat16* op = kb16 + ((size_t)bh * T_ + t0) * HS + d;
  float powc = c;
  for (int i = 0; i < SEGLEN; ++i) {
    float val = fmaf(powc, hin, kp[(size_t)i * HS]);
    powc *= c;
    float ss = val * val;
#pragma unroll
    for (int off = 1; off < 64; off <<= 1) ss += __shfl_xor(ss, off, 64);
    float scale = bk / (sqrtf(ss) + 1e-6f);
    op[(size_t)i * HS] = __float2bfloat16(val * scale);
  }
}

// ---------------- v build: shift-mix, normalize, scale; writes TRANSPOSED bf16 ------
// xv (B*T, C) f32 -> vt (B,NH,HS,T) bf16
__global__ __launch_bounds__(256) void vbuild_t(const float* __restrict__ xv,
                                                const float* __restrict__ v_coef,
                                                const float* __restrict__ value_beta,
                                                __hip_bfloat16* __restrict__ vt) {
  __shared__ __hip_bfloat16 sm[64][73];
  int t0 = blockIdx.x * 64;
  int bh = blockIdx.y;
  int h = bh % NH, b = bh / NH;
  int w = threadIdx.x >> 6, lane = threadIdx.x & 63;
  float vc = v_coef[h];
  float vb = __expf(fminf(value_beta[h] * 10.f, 5.f));
  for (int i = 0; i < 16; ++i) {
    int tl = w * 16 + i;
    int t = t0 + tl;
    const float* xp = xv + ((size_t)b * T_ + t) * C_ + h * HS + lane;
    float x0 = *xp;
    float x1 = (t + 1 < T_) ? xp[C_] : 0.f;
    float vf = (1.f - vc) * x1 + vc * x0;
    float ss = vf * vf;
#pragma unroll
    for (int off = 1; off < 64; off <<= 1) ss += __shfl_xor(ss, off, 64);
    sm[tl][lane] = __float2bfloat16(vf * vb / (sqrtf(ss) + 1e-6f));
  }
  __syncthreads();
  int d = threadIdx.x >> 3;   // 0..31
  int c = threadIdx.x & 7;    // 0..7
  for (int i = 0; i < 2; ++i) {
    int dd = d + i * 32;
    short8 v;
#pragma unroll
    for (int k = 0; k < 8; ++k)
      v[k] = (short)((const unsigned short*)&sm[c * 8 + k][dd])[0];
    *(short8*)((unsigned short*)vt + ((size_t)bh * HS + dd) * T_ + t0 + c * 8) = v;
  }
}

// ---------------- zero y rows at t=0 -------------------------------------------------
__global__ void yzero(float* __restrict__ y) {
  int i = blockIdx.x * 256 + threadIdx.x;
  if (i < B_ * C_) {
    int b = i / C_, c = i % C_;
    y[(size_t)b * T_ * C_ + c] = 0.f;
  }
}

// ---------------- MFMA flash attention, fixed-shift softmax -------------------------
// Kg: (B,NH,T,HS) bf16 (rows are both Q and K). Vtg: (B,NH,HS,T) bf16. Y: (B,T,C) f32.
__global__ __launch_bounds__(256) void attn_mfma(const __hip_bfloat16* __restrict__ Kg,
                                                 const __hip_bfloat16* __restrict__ Vtg,
                                                 const float* __restrict__ kernel_beta,
                                                 float* __restrict__ Y) {
  __shared__ __hip_bfloat16 Kt[64][72];       // padded rows: 144B stride
  __shared__ __hip_bfloat16 Vt[64][72];       // rows = d, cols = j-local
  __shared__ __hip_bfloat16 Pt[4][16][72];    // per-wave P slice
  int qb = blockIdx.x, bh = blockIdx.y;
  int b = bh / NH, h = bh % NH;
  int w = threadIdx.x >> 6, lane = threadIdx.x & 63;
  int qs = 1 + qb * 64;
  float bk = __expf(fminf(kernel_beta[h] * 10.f, 5.f));
  float m0 = bk * bk;  // fixed softmax shift (scores bounded by bk^2)
  const unsigned short* Kh = (const unsigned short*)Kg + (size_t)bh * T_ * HS;
  const unsigned short* Vh = (const unsigned short*)Vtg + (size_t)bh * HS * T_;

  // stage Q rows (clamped at T-1) into Kt, pull frags to regs
  {
    int r0 = w * 16 + (lane >> 3), c = lane & 7;
#pragma unroll
    for (int i = 0; i < 2; ++i) {
      int r = r0 + i * 8;
      int gr = qs + r; if (gr > T_ - 1) gr = T_ - 1;
      *(short8*)(&Kt[r][c * 8]) = *(const short8*)(Kh + (size_t)gr * HS + c * 8);
    }
  }
  __syncthreads();
  short8 qf[2];
  qf[0] = *(const short8*)(&Kt[w * 16 + (lane & 15)][(lane >> 4) * 8]);
  qf[1] = *(const short8*)(&Kt[w * 16 + (lane & 15)][32 + (lane >> 4) * 8]);
  __syncthreads();

  f32x4 accO[4];
  f32x4 zero = {0.f, 0.f, 0.f, 0.f};
#pragma unroll
  for (int i = 0; i < 4; ++i) accO[i] = zero;
  float lsum[4] = {0.f, 0.f, 0.f, 0.f};

  for (int kt = 0; kt <= qb; ++kt) {
    int j0 = kt * 64;
    {
      int r0 = w * 16 + (lane >> 3), c = lane & 7;
#pragma unroll
      for (int i = 0; i < 2; ++i) {
        int r = r0 + i * 8;
        *(short8*)(&Kt[r][c * 8]) = *(const short8*)(Kh + (size_t)(j0 + r) * HS + c * 8);
        *(short8*)(&Vt[r][c * 8]) = *(const short8*)(Vh + (size_t)r * T_ + j0 + c * 8);
      }
    }
    __syncthreads();
    // S = Q K^T  (16 q-rows x 64 j per wave)
    f32x4 s[4];
#pragma unroll
    for (int nt = 0; nt < 4; ++nt) {
      s[nt] = zero;
#pragma unroll
      for (int ks = 0; ks < 2; ++ks) {
        short8 bf = *(const short8*)(&Kt[nt * 16 + (lane & 15)][ks * 32 + (lane >> 4) * 8]);
        s[nt] = __builtin_amdgcn_mfma_f32_16x16x32_bf16(qf[ks], bf, s[nt], 0, 0, 0);
      }
    }
    // exp + causal mask + write P (bf16) to this wave's LDS slice
#pragma unroll
    for (int nt = 0; nt < 4; ++nt) {
#pragma unroll
      for (int r = 0; r < 4; ++r) {
        int j = j0 + nt * 16 + (lane & 15);
        int tq = qs + w * 16 + (lane >> 4) * 4 + r;
        float p = (j < tq) ? __expf(s[nt][r] - m0) : 0.f;
        lsum[r] += p;
        Pt[w][(lane >> 4) * 4 + r][nt * 16 + (lane & 15)] = __float2bfloat16(p);
      }
    }
    // O += P V   (A = P from LDS, B = Vt rows)
#pragma unroll
    for (int nt = 0; nt < 4; ++nt) {
#pragma unroll
      for (int ks = 0; ks < 2; ++ks) {
        short8 pa = *(const short8*)(&Pt[w][lane & 15][ks * 32 + (lane >> 4) * 8]);
        short8 vf = *(const short8*)(&Vt[nt * 16 + (lane & 15)][ks * 32 + (lane >> 4) * 8]);
        accO[nt] = __builtin_amdgcn_mfma_f32_16x16x32_bf16(pa, vf, accO[nt], 0, 0, 0);
      }
    }
    __syncthreads();
  }

  // denominator: reduce lsum over the 16-lane row-group, then write O / l
#pragma unroll
  for (int r = 0; r < 4; ++r) {
    float v = lsum[r];
    v += __shfl_xor(v, 1, 64);
    v += __shfl_xor(v, 2, 64);
    v += __shfl_xor(v, 4, 64);
    v += __shfl_xor(v, 8, 64);
    lsum[r] = 1.f / v;
  }
#pragma unroll
  for (int r = 0; r < 4; ++r) {
    int tq = qs + w * 16 + (lane >> 4) * 4 + r;
    if (tq < T_) {
      float* yp = Y + ((size_t)b * T_ + tq) * C_ + h * HS;
#pragma unroll
      for (int nt = 0; nt < 4; ++nt)
        yp[nt * 16 + (lane & 15)] = accO[nt][r] * lsum[r];
    }
  }
}

extern "C" void kernel_launch(void* const* d_in, const int* in_sizes, int n_in,
                              void* d_out, int out_size, void* d_ws, size_t ws_size,
                              hipStream_t stream) {
  const float* x          = (const float*)d_in[0];
  const float* W_la       = (const float*)d_in[1];
  const float* la_coef    = (const float*)d_in[2];
  const float* W_v        = (const float*)d_in[3];
  const float* v_coef     = (const float*)d_in[4];
  const float* kernel_bet = (const float*)d_in[5];
  const float* value_bet  = (const float*)d_in[6];
  const float* W_proj     = (const float*)d_in[7];
  float* out = (float*)d_out;

  float* ws = (float*)d_ws;
  const size_t NTOK = (size_t)B_ * T_ * C_;  // 3,145,728
  float* u    = ws;              // (B*T, C)  f32 — reused as y after scan consumes it
  float* xv   = u + NTOK;        // (B*T, C)  f32
  float* kbuf = xv + NTOK;       // (B,NH,T,HS) f32 scan partials
  float* segend  = kbuf + NTOK;                         // 24576
  float* carryin = segend + (size_t)B_ * NH * NSEG * HS; // 24576
  __hip_bfloat16* kb16 = (__hip_bfloat16*)(carryin + (size_t)B_ * NH * NSEG * HS); // NTOK bf16
  __hip_bfloat16* vt16 = kb16 + NTOK;                   // NTOK bf16 (transposed v)
  float* ybuf = u;               // alias: u dead after scan_a

  const int M = B_ * T_;  // 4096

  dim3 ggrid(M / 64, C_ / 64);
  gemm_nt_f32<<<ggrid, 256, 0, stream>>>(x, W_la, u, M, C_, C_);
  gemm_nt_f32<<<ggrid, 256, 0, stream>>>(x, W_v, xv, M, C_, C_);

  scan_a<<<dim3(B_ * NH * NSEG / 4), 256, 0, stream>>>(u, la_coef, kbuf, segend);
  scan_b<<<dim3((B_ * NH * HS + 255) / 256), 256, 0, stream>>>(la_coef, segend, carryin);
  scan_c_norm<<<dim3(B_ * NH * NSEG / 4), 256, 0, stream>>>(la_coef, kernel_bet, carryin, kbuf, kb16);

  vbuild_t<<<dim3(T_ / 64, B_ * NH), 256, 0, stream>>>(xv, v_coef, value_bet, vt16);

  yzero<<<dim3((B_ * C_ + 255) / 256), 256, 0, stream>>>(ybuf);
  attn_mfma<<<dim3(T_ / 64, B_ * NH), 256, 0, stream>>>(kb16, vt16, kernel_bet, ybuf);

  gemm_nt_f32<<<ggrid, 256, 0, stream>>>(ybuf, W_proj, out, M, C_, C_);
}

// Round 3
// 167.113 us; speedup vs baseline: 13.3580x; 2.1691x over previous
//
#include <hip/hip_runtime.h>
#include <hip/hip_bf16.h>
#include <math.h>

#define B_   2
#define T_   2048
#define C_   768
#define NH   12
#define HS   64
#define NSEG 32
#define SEGLEN 64
#define CX   1536   // uxv row stride (u | xv)

typedef __attribute__((ext_vector_type(8))) short short8;
typedef __attribute__((ext_vector_type(4))) short short4v;
typedef __attribute__((ext_vector_type(4))) float f32x4;

static __device__ inline unsigned short f2b(float f) {
  __hip_bfloat16 h = __float2bfloat16(f);
  unsigned short u;
  __builtin_memcpy(&u, &h, 2);
  return u;
}

#define GLOAD_LDS16(gp, lp)                                                        \
  __builtin_amdgcn_global_load_lds((const __attribute__((address_space(1))) void*)(gp), \
                                   (__attribute__((address_space(3))) void*)(lp), 16, 0, 0)

// ---------------- f32 -> bf16 cast (vectorized) --------------------------------------
__global__ __launch_bounds__(256) void cast_f32_bf16(const float* __restrict__ s,
                                                     __hip_bfloat16* __restrict__ d, int n4) {
  int i = blockIdx.x * 256 + threadIdx.x;
  int st = gridDim.x * 256;
  for (; i < n4; i += st) {
    float4 v = ((const float4*)s)[i];
    short4v o;
    o.x = (short)f2b(v.x); o.y = (short)f2b(v.y); o.z = (short)f2b(v.z); o.w = (short)f2b(v.w);
    *(short4v*)((unsigned short*)d + (size_t)i * 4) = o;
  }
}

// ---------------- bf16 MFMA GEMM: C[m,n] = sum_k A[m,k] * Bw[n,k], C f32 -------------
// 128x128 tile, BK=64, 4 waves (2x2), global_load_lds staging, XOR-swizzled LDS.
__global__ __launch_bounds__(256) void gemm_bf16(const __hip_bfloat16* __restrict__ A,
                                                 const __hip_bfloat16* __restrict__ Bw,
                                                 float* __restrict__ C,
                                                 int M, int N, int K) {
  __shared__ __hip_bfloat16 As[128 * 64];
  __shared__ __hip_bfloat16 Bs[128 * 64];
  const int tid = threadIdx.x;
  const int w = tid >> 6, lane = tid & 63;
  const int bm = blockIdx.x * 128, bn = blockIdx.y * 128;
  const int wr = w >> 1, wc = w & 1;

  f32x4 acc[4][4];
#pragma unroll
  for (int i = 0; i < 4; ++i)
#pragma unroll
    for (int j = 0; j < 4; ++j) acc[i][j] = (f32x4){0.f, 0.f, 0.f, 0.f};

  const int srow = (lane >> 3);          // staging row-within-chunk
  const int soff0 = (lane & 7) * 16;     // staging byte col (pre-swizzle)
  const int sw = (lane & 7) << 4;        // read swizzle (row&7)<<4 with row&7 == lane&7

  for (int k0 = 0; k0 < K; k0 += 64) {
    __syncthreads();
#pragma unroll
    for (int c = 0; c < 8; ++c) {
      int gc = w * 8 + c;
      int isB = gc >> 4;        // chunks 0..15 -> A, 16..31 -> B
      int ci = gc & 15;
      int row = ci * 8 + srow;
      int soff = soff0 ^ ((row & 7) << 4);   // inverse-swizzled global source
      const __hip_bfloat16* gp =
          (isB ? Bw + (size_t)(bn + row) * K : A + (size_t)(bm + row) * K) + k0 + (soff >> 1);
      __hip_bfloat16* lp = (isB ? Bs : As) + ci * 512;  // wave-uniform, linear dest
      GLOAD_LDS16(gp, lp);
    }
    __syncthreads();
#pragma unroll
    for (int ks = 0; ks < 2; ++ks) {
      short8 af[4], bf[4];
      const int colb = ks * 64 + (lane >> 4) * 16;
#pragma unroll
      for (int i = 0; i < 4; ++i) {
        int ra = wr * 64 + i * 16 + (lane & 15);
        int rb = wc * 64 + i * 16 + (lane & 15);
        af[i] = *(const short8*)((const char*)As + ra * 128 + (colb ^ sw));
        bf[i] = *(const short8*)((const char*)Bs + rb * 128 + (colb ^ sw));
      }
#pragma unroll
      for (int i = 0; i < 4; ++i)
#pragma unroll
        for (int j = 0; j < 4; ++j)
          acc[i][j] = __builtin_amdgcn_mfma_f32_16x16x32_bf16(af[i], bf[j], acc[i][j], 0, 0, 0);
    }
  }
#pragma unroll
  for (int i = 0; i < 4; ++i) {
#pragma unroll
    for (int r = 0; r < 4; ++r) {
      int m = bm + wr * 64 + i * 16 + (lane >> 4) * 4 + r;
      float* cp = C + (size_t)m * N + bn + wc * 64 + (lane & 15);
#pragma unroll
      for (int j = 0; j < 4; ++j) cp[j * 16] = acc[i][j][r];
    }
  }
}

// ---------------- Scan pass A: local leaky-average per segment, IN PLACE on u -------
__global__ __launch_bounds__(256) void scan_a(float* __restrict__ uxv,
                                              const float* __restrict__ la_coef,
                                              float* __restrict__ segend) {
  int cid = blockIdx.x * 4 + (threadIdx.x >> 6);  // bh*NSEG + seg
  int d   = threadIdx.x & 63;
  int seg = cid & (NSEG - 1);
  int bh  = cid >> 5;
  int h   = bh % NH;
  int b   = bh / NH;
  float c  = la_coef[h];
  float oc = 1.f - c;
  int t0 = seg * SEGLEN;
  float* up = uxv + ((size_t)b * T_ + t0) * CX + h * HS + d;
  float y = 0.f;
  for (int i = 0; i < SEGLEN; ++i) {
    float uv = up[(size_t)i * CX];
    y = fmaf(c, y, oc * uv);
    up[(size_t)i * CX] = y;
  }
  segend[(size_t)cid * HS + d] = y;
}

// ---------------- Scan pass B: sequential combine of segment carries ----------------
__global__ __launch_bounds__(256) void scan_b(const float* __restrict__ la_coef,
                                              const float* __restrict__ segend,
                                              float* __restrict__ carryin) {
  int s = blockIdx.x * 256 + threadIdx.x;  // (b,h,d)
  if (s >= B_ * NH * HS) return;
  int d  = s & 63;
  int bh = s >> 6;
  int h  = bh % NH;
  float c = la_coef[h];
  float cl = c;
#pragma unroll
  for (int i = 0; i < 6; ++i) cl *= cl;  // c^64
  float h0 = 0.f;
  for (int seg = 0; seg < NSEG; ++seg) {
    int cid = bh * NSEG + seg;
    carryin[(size_t)cid * HS + d] = h0;
    h0 = fmaf(cl, h0, segend[(size_t)cid * HS + d]);
  }
}

// ---------------- Scan pass C + k normalization, writes bf16 ------------------------
__global__ __launch_bounds__(256) void scan_c_norm(const float* __restrict__ la_coef,
                                                   const float* __restrict__ kernel_beta,
                                                   const float* __restrict__ carryin,
                                                   const float* __restrict__ uxv,
                                                   __hip_bfloat16* __restrict__ kb16) {
  int cid = blockIdx.x * 4 + (threadIdx.x >> 6);
  int d   = threadIdx.x & 63;
  int seg = cid & (NSEG - 1);
  int bh  = cid >> 5;
  int h   = bh % NH;
  int b   = bh / NH;
  float c  = la_coef[h];
  float bk = __expf(fminf(kernel_beta[h] * 10.f, 5.f));
  float hin = carryin[(size_t)cid * HS + d];
  int t0 = seg * SEGLEN;
  const float* kp = uxv + ((size_t)b * T_ + t0) * CX + h * HS + d;
  __hip_bfloat16* op = kb16 + ((size_t)bh * T_ + t0) * HS + d;
  float powc = c;
  for (int i = 0; i < SEGLEN; ++i) {
    float val = fmaf(powc, hin, kp[(size_t)i * CX]);
    powc *= c;
    float ss = val * val;
#pragma unroll
    for (int off = 1; off < 64; off <<= 1) ss += __shfl_xor(ss, off, 64);
    float scale = bk / (sqrtf(ss) + 1e-6f);
    op[(size_t)i * HS] = __float2bfloat16(val * scale);
  }
}

// ---------------- v build: shift-mix, normalize, scale; writes TRANSPOSED bf16 ------
// uxv xv-part (B*T, CX offset 768) f32 -> vt (B,NH,HS,T) bf16
__global__ __launch_bounds__(256) void vbuild_t(const float* __restrict__ uxv,
                                                const float* __restrict__ v_coef,
                                                const float* __restrict__ value_beta,
                                                __hip_bfloat16* __restrict__ vt) {
  __shared__ __hip_bfloat16 sm[64][73];
  int t0 = blockIdx.x * 64;
  int bh = blockIdx.y;
  int h = bh % NH, b = bh / NH;
  int w = threadIdx.x >> 6, lane = threadIdx.x & 63;
  float vc = v_coef[h];
  float vb = __expf(fminf(value_beta[h] * 10.f, 5.f));
  for (int i = 0; i < 16; ++i) {
    int tl = w * 16 + i;
    int t = t0 + tl;
    const float* xp = uxv + ((size_t)b * T_ + t) * CX + 768 + h * HS + lane;
    float x0 = *xp;
    float x1 = (t + 1 < T_) ? xp[CX] : 0.f;
    float vf = (1.f - vc) * x1 + vc * x0;
    float ss = vf * vf;
#pragma unroll
    for (int off = 1; off < 64; off <<= 1) ss += __shfl_xor(ss, off, 64);
    sm[tl][lane] = __float2bfloat16(vf * vb / (sqrtf(ss) + 1e-6f));
  }
  __syncthreads();
  int d = threadIdx.x >> 3;   // 0..31
  int c = threadIdx.x & 7;    // 0..7
  for (int i = 0; i < 2; ++i) {
    int dd = d + i * 32;
    short8 v;
#pragma unroll
    for (int k = 0; k < 8; ++k)
      v[k] = (short)((const unsigned short*)&sm[c * 8 + k][dd])[0];
    *(short8*)((unsigned short*)vt + ((size_t)bh * HS + dd) * T_ + t0 + c * 8) = v;
  }
}

// ---------------- zero y rows at t=0 (bf16) ------------------------------------------
__global__ void yzero(__hip_bfloat16* __restrict__ y) {
  int i = blockIdx.x * 256 + threadIdx.x;
  if (i < B_ * C_) {
    int b = i / C_, c = i % C_;
    y[(size_t)b * T_ * C_ + c] = __float2bfloat16(0.f);
  }
}

// ---------------- MFMA flash attention, fixed-shift softmax, bf16 out ---------------
__global__ __launch_bounds__(256) void attn_mfma(const __hip_bfloat16* __restrict__ Kg,
                                                 const __hip_bfloat16* __restrict__ Vtg,
                                                 const float* __restrict__ kernel_beta,
                                                 __hip_bfloat16* __restrict__ Y) {
  __shared__ __hip_bfloat16 Kt[64][72];
  __shared__ __hip_bfloat16 Vt[64][72];
  __shared__ __hip_bfloat16 Pt[4][16][72];
  int qb = blockIdx.x, bh = blockIdx.y;
  int b = bh / NH, h = bh % NH;
  int w = threadIdx.x >> 6, lane = threadIdx.x & 63;
  int qs = 1 + qb * 64;
  float bk = __expf(fminf(kernel_beta[h] * 10.f, 5.f));
  float m0 = bk * bk;
  const unsigned short* Kh = (const unsigned short*)Kg + (size_t)bh * T_ * HS;
  const unsigned short* Vh = (const unsigned short*)Vtg + (size_t)bh * HS * T_;

  {
    int r0 = w * 16 + (lane >> 3), c = lane & 7;
#pragma unroll
    for (int i = 0; i < 2; ++i) {
      int r = r0 + i * 8;
      int gr = qs + r; if (gr > T_ - 1) gr = T_ - 1;
      *(short8*)(&Kt[r][c * 8]) = *(const short8*)(Kh + (size_t)gr * HS + c * 8);
    }
  }
  __syncthreads();
  short8 qf[2];
  qf[0] = *(const short8*)(&Kt[w * 16 + (lane & 15)][(lane >> 4) * 8]);
  qf[1] = *(const short8*)(&Kt[w * 16 + (lane & 15)][32 + (lane >> 4) * 8]);
  __syncthreads();

  f32x4 accO[4];
  f32x4 zero = {0.f, 0.f, 0.f, 0.f};
#pragma unroll
  for (int i = 0; i < 4; ++i) accO[i] = zero;
  float lsum[4] = {0.f, 0.f, 0.f, 0.f};

  for (int kt = 0; kt <= qb; ++kt) {
    int j0 = kt * 64;
    {
      int r0 = w * 16 + (lane >> 3), c = lane & 7;
#pragma unroll
      for (int i = 0; i < 2; ++i) {
        int r = r0 + i * 8;
        *(short8*)(&Kt[r][c * 8]) = *(const short8*)(Kh + (size_t)(j0 + r) * HS + c * 8);
        *(short8*)(&Vt[r][c * 8]) = *(const short8*)(Vh + (size_t)r * T_ + j0 + c * 8);
      }
    }
    __syncthreads();
    f32x4 s[4];
#pragma unroll
    for (int nt = 0; nt < 4; ++nt) {
      s[nt] = zero;
#pragma unroll
      for (int ks = 0; ks < 2; ++ks) {
        short8 bf = *(const short8*)(&Kt[nt * 16 + (lane & 15)][ks * 32 + (lane >> 4) * 8]);
        s[nt] = __builtin_amdgcn_mfma_f32_16x16x32_bf16(qf[ks], bf, s[nt], 0, 0, 0);
      }
    }
#pragma unroll
    for (int nt = 0; nt < 4; ++nt) {
#pragma unroll
      for (int r = 0; r < 4; ++r) {
        int j = j0 + nt * 16 + (lane & 15);
        int tq = qs + w * 16 + (lane >> 4) * 4 + r;
        float p = (j < tq) ? __expf(s[nt][r] - m0) : 0.f;
        lsum[r] += p;
        Pt[w][(lane >> 4) * 4 + r][nt * 16 + (lane & 15)] = __float2bfloat16(p);
      }
    }
#pragma unroll
    for (int nt = 0; nt < 4; ++nt) {
#pragma unroll
      for (int ks = 0; ks < 2; ++ks) {
        short8 pa = *(const short8*)(&Pt[w][lane & 15][ks * 32 + (lane >> 4) * 8]);
        short8 vf = *(const short8*)(&Vt[nt * 16 + (lane & 15)][ks * 32 + (lane >> 4) * 8]);
        accO[nt] = __builtin_amdgcn_mfma_f32_16x16x32_bf16(pa, vf, accO[nt], 0, 0, 0);
      }
    }
    __syncthreads();
  }

#pragma unroll
  for (int r = 0; r < 4; ++r) {
    float v = lsum[r];
    v += __shfl_xor(v, 1, 64);
    v += __shfl_xor(v, 2, 64);
    v += __shfl_xor(v, 4, 64);
    v += __shfl_xor(v, 8, 64);
    lsum[r] = 1.f / v;
  }
#pragma unroll
  for (int r = 0; r < 4; ++r) {
    int tq = qs + w * 16 + (lane >> 4) * 4 + r;
    if (tq < T_) {
      __hip_bfloat16* yp = Y + ((size_t)b * T_ + tq) * C_ + h * HS;
#pragma unroll
      for (int nt = 0; nt < 4; ++nt)
        yp[nt * 16 + (lane & 15)] = __float2bfloat16(accO[nt][r] * lsum[r]);
    }
  }
}

extern "C" void kernel_launch(void* const* d_in, const int* in_sizes, int n_in,
                              void* d_out, int out_size, void* d_ws, size_t ws_size,
                              hipStream_t stream) {
  const float* x          = (const float*)d_in[0];
  const float* W_la       = (const float*)d_in[1];
  const float* la_coef    = (const float*)d_in[2];
  const float* W_v        = (const float*)d_in[3];
  const float* v_coef     = (const float*)d_in[4];
  const float* kernel_bet = (const float*)d_in[5];
  const float* value_bet  = (const float*)d_in[6];
  const float* W_proj     = (const float*)d_in[7];
  float* out = (float*)d_out;

  float* ws = (float*)d_ws;
  const size_t NTOK = (size_t)B_ * T_ * C_;        // 3,145,728
  const size_t NSEGTOT = (size_t)B_ * NH * NSEG * HS;  // 49,152
  float* uxv     = ws;                              // (B*T, 1536) f32
  float* segend  = uxv + (size_t)B_ * T_ * CX;
  float* carryin = segend + NSEGTOT;
  __hip_bfloat16* kb16 = (__hip_bfloat16*)(carryin + NSEGTOT);  // (B,NH,T,HS)
  __hip_bfloat16* vt16 = kb16 + NTOK;                           // (B,NH,HS,T)
  __hip_bfloat16* xb   = vt16 + NTOK;                           // (B*T,C) bf16; reused as y
  __hip_bfloat16* Wcat = xb + NTOK;                             // (1536,768) bf16
  __hip_bfloat16* Wpb  = Wcat + (size_t)CX * C_;                // (768,768) bf16
  __hip_bfloat16* yb   = xb;  // alias: xb dead after gemm1

  const int M = B_ * T_;  // 4096

  // casts
  cast_f32_bf16<<<2048, 256, 0, stream>>>(x, xb, (int)(NTOK / 4));
  cast_f32_bf16<<<576, 256, 0, stream>>>(W_la, Wcat, C_ * C_ / 4);
  cast_f32_bf16<<<576, 256, 0, stream>>>(W_v, Wcat + (size_t)C_ * C_, C_ * C_ / 4);
  cast_f32_bf16<<<576, 256, 0, stream>>>(W_proj, Wpb, C_ * C_ / 4);

  // fused projections: uxv = xb @ [W_la; W_v]^T
  gemm_bf16<<<dim3(M / 128, CX / 128), 256, 0, stream>>>(xb, Wcat, uxv, M, CX, C_);

  // leaky-average scan (in place on u) + combine + normalize -> kb16
  scan_a<<<dim3(B_ * NH * NSEG / 4), 256, 0, stream>>>(uxv, la_coef, segend);
  scan_b<<<dim3((B_ * NH * HS + 255) / 256), 256, 0, stream>>>(la_coef, segend, carryin);
  scan_c_norm<<<dim3(B_ * NH * NSEG / 4), 256, 0, stream>>>(la_coef, kernel_bet, carryin, uxv, kb16);

  // v path
  vbuild_t<<<dim3(T_ / 64, B_ * NH), 256, 0, stream>>>(uxv, v_coef, value_bet, vt16);

  // attention -> yb (bf16)
  yzero<<<dim3((B_ * C_ + 255) / 256), 256, 0, stream>>>(yb);
  attn_mfma<<<dim3(T_ / 64, B_ * NH), 256, 0, stream>>>(kb16, vt16, kernel_bet, yb);

  // out = y @ W_proj^T
  gemm_bf16<<<dim3(M / 128, C_ / 128), 256, 0, stream>>>(yb, Wpb, out, M, C_, C_);
}

// Round 4
// 149.987 us; speedup vs baseline: 14.8832x; 1.1142x over previous
//
#include <hip/hip_runtime.h>
#include <hip/hip_bf16.h>
#include <math.h>

#define B_   2
#define T_   2048
#define C_   768
#define NH   12
#define HS   64
#define NSEG 64
#define SEGLEN 32
#define CX   1536   // uxv row stride (u | xv)

typedef __attribute__((ext_vector_type(8))) short short8;
typedef __attribute__((ext_vector_type(4))) short short4v;
typedef __attribute__((ext_vector_type(4))) float f32x4;

static __device__ inline unsigned short f2b(float f) {
  __hip_bfloat16 h = __float2bfloat16(f);
  unsigned short u;
  __builtin_memcpy(&u, &h, 2);
  return u;
}

#define GLOAD_LDS16(gp, lp)                                                        \
  __builtin_amdgcn_global_load_lds((const __attribute__((address_space(1))) void*)(gp), \
                                   (__attribute__((address_space(3))) void*)(lp), 16, 0, 0)

// ---------------- fused f32 -> bf16 casts (x, W_la|W_v -> Wcat, W_proj) -------------
__global__ __launch_bounds__(256) void cast_all(const float* __restrict__ x,
                                                const float* __restrict__ wla,
                                                const float* __restrict__ wv,
                                                const float* __restrict__ wp,
                                                __hip_bfloat16* __restrict__ xb,
                                                __hip_bfloat16* __restrict__ wcat,
                                                __hip_bfloat16* __restrict__ wpb) {
  const int NX4 = (B_ * T_ * C_) / 4;     // 786432
  const int NW4 = (C_ * C_) / 4;          // 147456
  const int TOT = NX4 + 3 * NW4;
  int i = blockIdx.x * 256 + threadIdx.x;
  int st = gridDim.x * 256;
  for (; i < TOT; i += st) {
    const float* s;
    unsigned short* d;
    if (i < NX4) { s = x + (size_t)i * 4; d = (unsigned short*)xb + (size_t)i * 4; }
    else if (i < NX4 + NW4) { int j = i - NX4; s = wla + (size_t)j * 4; d = (unsigned short*)wcat + (size_t)j * 4; }
    else if (i < NX4 + 2 * NW4) { int j = i - NX4 - NW4; s = wv + (size_t)j * 4; d = (unsigned short*)wcat + (size_t)(C_ * C_) + (size_t)j * 4; }
    else { int j = i - NX4 - 2 * NW4; s = wp + (size_t)j * 4; d = (unsigned short*)wpb + (size_t)j * 4; }
    float4 v = *(const float4*)s;
    short4v o;
    o.x = (short)f2b(v.x); o.y = (short)f2b(v.y); o.z = (short)f2b(v.z); o.w = (short)f2b(v.w);
    *(short4v*)d = o;
  }
}

// ---------------- bf16 MFMA GEMM: C[m,n] = sum_k A[m,k] * Bw[n,k], C f32 -------------
__global__ __launch_bounds__(256) void gemm_bf16(const __hip_bfloat16* __restrict__ A,
                                                 const __hip_bfloat16* __restrict__ Bw,
                                                 float* __restrict__ C,
                                                 int M, int N, int K) {
  __shared__ __hip_bfloat16 As[128 * 64];
  __shared__ __hip_bfloat16 Bs[128 * 64];
  const int tid = threadIdx.x;
  const int w = tid >> 6, lane = tid & 63;
  const int bm = blockIdx.x * 128, bn = blockIdx.y * 128;
  const int wr = w >> 1, wc = w & 1;

  f32x4 acc[4][4];
#pragma unroll
  for (int i = 0; i < 4; ++i)
#pragma unroll
    for (int j = 0; j < 4; ++j) acc[i][j] = (f32x4){0.f, 0.f, 0.f, 0.f};

  const int srow = (lane >> 3);
  const int soff0 = (lane & 7) * 16;
  const int sw = (lane & 7) << 4;

  for (int k0 = 0; k0 < K; k0 += 64) {
    __syncthreads();
#pragma unroll
    for (int c = 0; c < 8; ++c) {
      int gc = w * 8 + c;
      int isB = gc >> 4;
      int ci = gc & 15;
      int row = ci * 8 + srow;
      int soff = soff0 ^ ((row & 7) << 4);
      const __hip_bfloat16* gp =
          (isB ? Bw + (size_t)(bn + row) * K : A + (size_t)(bm + row) * K) + k0 + (soff >> 1);
      __hip_bfloat16* lp = (isB ? Bs : As) + ci * 512;
      GLOAD_LDS16(gp, lp);
    }
    __syncthreads();
#pragma unroll
    for (int ks = 0; ks < 2; ++ks) {
      short8 af[4], bf[4];
      const int colb = ks * 64 + (lane >> 4) * 16;
#pragma unroll
      for (int i = 0; i < 4; ++i) {
        int ra = wr * 64 + i * 16 + (lane & 15);
        int rb = wc * 64 + i * 16 + (lane & 15);
        af[i] = *(const short8*)((const char*)As + ra * 128 + (colb ^ sw));
        bf[i] = *(const short8*)((const char*)Bs + rb * 128 + (colb ^ sw));
      }
#pragma unroll
      for (int i = 0; i < 4; ++i)
#pragma unroll
        for (int j = 0; j < 4; ++j)
          acc[i][j] = __builtin_amdgcn_mfma_f32_16x16x32_bf16(af[i], bf[j], acc[i][j], 0, 0, 0);
    }
  }
#pragma unroll
  for (int i = 0; i < 4; ++i) {
#pragma unroll
    for (int r = 0; r < 4; ++r) {
      int m = bm + wr * 64 + i * 16 + (lane >> 4) * 4 + r;
      float* cp = C + (size_t)m * N + bn + wc * 64 + (lane & 15);
#pragma unroll
      for (int j = 0; j < 4; ++j) cp[j * 16] = acc[i][j][r];
    }
  }
}

// ---------------- Scan pass A: local leaky-average per segment, IN PLACE on u -------
__global__ __launch_bounds__(256) void scan_a(float* __restrict__ uxv,
                                              const float* __restrict__ la_coef,
                                              float* __restrict__ segend) {
  int cid = blockIdx.x * 4 + (threadIdx.x >> 6);  // bh*NSEG + seg
  int d   = threadIdx.x & 63;
  int seg = cid & (NSEG - 1);
  int bh  = cid >> 6;
  int h   = bh % NH;
  int b   = bh / NH;
  float c  = la_coef[h];
  float oc = 1.f - c;
  int t0 = seg * SEGLEN;
  float* up = uxv + ((size_t)b * T_ + t0) * CX + h * HS + d;
  float y = 0.f;
  for (int i = 0; i < SEGLEN; ++i) {
    float uv = up[(size_t)i * CX];
    y = fmaf(c, y, oc * uv);
    up[(size_t)i * CX] = y;
  }
  segend[(size_t)cid * HS + d] = y;
}

// ---------------- Scan pass B: sequential combine of segment carries ----------------
__global__ __launch_bounds__(256) void scan_b(const float* __restrict__ la_coef,
                                              const float* __restrict__ segend,
                                              float* __restrict__ carryin) {
  int s = blockIdx.x * 256 + threadIdx.x;  // (b,h,d)
  if (s >= B_ * NH * HS) return;
  int d  = s & 63;
  int bh = s >> 6;
  int h  = bh % NH;
  float c = la_coef[h];
  float cl = c;
#pragma unroll
  for (int i = 0; i < 5; ++i) cl *= cl;  // c^32
  float h0 = 0.f;
  for (int seg = 0; seg < NSEG; ++seg) {
    int cid = bh * NSEG + seg;
    carryin[(size_t)cid * HS + d] = h0;
    h0 = fmaf(cl, h0, segend[(size_t)cid * HS + d]);
  }
}

// ---------------- Scan pass C + k normalization, writes bf16 ------------------------
__global__ __launch_bounds__(256) void scan_c_norm(const float* __restrict__ la_coef,
                                                   const float* __restrict__ kernel_beta,
                                                   const float* __restrict__ carryin,
                                                   const float* __restrict__ uxv,
                                                   __hip_bfloat16* __restrict__ kb16) {
  int cid = blockIdx.x * 4 + (threadIdx.x >> 6);
  int d   = threadIdx.x & 63;
  int seg = cid & (NSEG - 1);
  int bh  = cid >> 6;
  int h   = bh % NH;
  int b   = bh / NH;
  float c  = la_coef[h];
  float bk = __expf(fminf(kernel_beta[h] * 10.f, 5.f));
  float hin = carryin[(size_t)cid * HS + d];
  int t0 = seg * SEGLEN;
  const float* kp = uxv + ((size_t)b * T_ + t0) * CX + h * HS + d;
  __hip_bfloat16* op = kb16 + ((size_t)bh * T_ + t0) * HS + d;
  float powc = c;
  for (int i = 0; i < SEGLEN; ++i) {
    float val = fmaf(powc, hin, kp[(size_t)i * CX]);
    powc *= c;
    float ss = val * val;
#pragma unroll
    for (int off = 1; off < 64; off <<= 1) ss += __shfl_xor(ss, off, 64);
    float scale = bk / (sqrtf(ss) + 1e-6f);
    op[(size_t)i * HS] = __float2bfloat16(val * scale);
  }
}

// ---------------- v build: shift-mix, normalize, scale; writes TRANSPOSED bf16 ------
__global__ __launch_bounds__(256) void vbuild_t(const float* __restrict__ uxv,
                                                const float* __restrict__ v_coef,
                                                const float* __restrict__ value_beta,
                                                __hip_bfloat16* __restrict__ vt) {
  __shared__ __hip_bfloat16 sm[64][73];
  int t0 = blockIdx.x * 64;
  int bh = blockIdx.y;
  int h = bh % NH, b = bh / NH;
  int w = threadIdx.x >> 6, lane = threadIdx.x & 63;
  float vc = v_coef[h];
  float vb = __expf(fminf(value_beta[h] * 10.f, 5.f));
  for (int i = 0; i < 16; ++i) {
    int tl = w * 16 + i;
    int t = t0 + tl;
    const float* xp = uxv + ((size_t)b * T_ + t) * CX + 768 + h * HS + lane;
    float x0 = *xp;
    float x1 = (t + 1 < T_) ? xp[CX] : 0.f;
    float vf = (1.f - vc) * x1 + vc * x0;
    float ss = vf * vf;
#pragma unroll
    for (int off = 1; off < 64; off <<= 1) ss += __shfl_xor(ss, off, 64);
    sm[tl][lane] = __float2bfloat16(vf * vb / (sqrtf(ss) + 1e-6f));
  }
  __syncthreads();
  int d = threadIdx.x >> 3;
  int c = threadIdx.x & 7;
  for (int i = 0; i < 2; ++i) {
    int dd = d + i * 32;
    short8 v;
#pragma unroll
    for (int k = 0; k < 8; ++k)
      v[k] = (short)((const unsigned short*)&sm[c * 8 + k][dd])[0];
    *(short8*)((unsigned short*)vt + ((size_t)bh * HS + dd) * T_ + t0 + c * 8) = v;
  }
}

// ---------------- attention v2: no barriers, frags direct from L2, swapped S^T ------
// Kg (B,NH,T,HS) bf16; Vtg (B,NH,HS,T) bf16; Y (B,T,C) bf16.
__global__ __launch_bounds__(256) void attn2(const __hip_bfloat16* __restrict__ Kg,
                                             const __hip_bfloat16* __restrict__ Vtg,
                                             const float* __restrict__ kernel_beta,
                                             __hip_bfloat16* __restrict__ Y) {
  __shared__ char Pl[8][2304];  // [wave*2+qset][16 rows x 144B]
  const int bh = blockIdx.y;
  const int b = bh / NH, h = bh % NH;
  const int w = threadIdx.x >> 6, lane = threadIdx.x & 63;
  const int q16 = lane & 15, lg = lane >> 4;
  const int i = blockIdx.x;  // 0..15
  // balanced chunk assignment: block total work is constant
  const int c = (w == 0) ? i : (w == 1) ? 31 - i : (w == 2) ? 32 + i : 63 - i;
  const int qstart = 1 + c * 32;
  float bk = __expf(fminf(kernel_beta[h] * 10.f, 5.f));
  float m0 = bk * bk;
  const unsigned short* Kh = (const unsigned short*)Kg + (size_t)bh * T_ * HS;
  const unsigned short* Vh = (const unsigned short*)Vtg + (size_t)bh * HS * T_;
  unsigned short* Yh = (unsigned short*)Y + (size_t)b * T_ * C_ + h * HS;

  if (i == 0 && w == 0) Yh[lane] = 0;  // t=0 row zero (bf16 zero bits)

  // Q fragments (B-operand layout): lane holds q-col = q16, d contiguous
  short8 qf[2][2];
#pragma unroll
  for (int qs = 0; qs < 2; ++qs) {
    int tq = qstart + qs * 16 + q16;
    if (tq > T_ - 1) tq = T_ - 1;
#pragma unroll
    for (int ks = 0; ks < 2; ++ks)
      qf[qs][ks] = *(const short8*)(Kh + (size_t)tq * HS + ks * 32 + lg * 8);
  }

  f32x4 zero = {0.f, 0.f, 0.f, 0.f};
  f32x4 accO[2][4];
#pragma unroll
  for (int qs = 0; qs < 2; ++qs)
#pragma unroll
    for (int mt = 0; mt < 4; ++mt) accO[qs][mt] = zero;
  float lsum[2] = {0.f, 0.f};

  char* pb0 = &Pl[w * 2 + 0][0] + q16 * 144;
  char* pb1 = &Pl[w * 2 + 1][0] + q16 * 144;

  const int NTT = (qstart + 94) >> 6;
  for (int kt = 0; kt < NTT; ++kt) {
    const int j0 = kt * 64;
    short8 kf[4][2], vf[4][2];
#pragma unroll
    for (int nt = 0; nt < 4; ++nt)
#pragma unroll
      for (int ks = 0; ks < 2; ++ks) {
        kf[nt][ks] = *(const short8*)(Kh + (size_t)(j0 + nt * 16 + q16) * HS + ks * 32 + lg * 8);
        vf[nt][ks] = *(const short8*)(Vh + (size_t)(nt * 16 + q16) * T_ + j0 + ks * 32 + lg * 8);
      }
#pragma unroll
    for (int qs = 0; qs < 2; ++qs) {
      const int tq = qstart + qs * 16 + q16;
      char* pb = qs ? pb1 : pb0;
      f32x4 s[4];
#pragma unroll
      for (int nt = 0; nt < 4; ++nt) {
        s[nt] = __builtin_amdgcn_mfma_f32_16x16x32_bf16(kf[nt][0], qf[qs][0], zero, 0, 0, 0);
        s[nt] = __builtin_amdgcn_mfma_f32_16x16x32_bf16(kf[nt][1], qf[qs][1], s[nt], 0, 0, 0);
      }
#pragma unroll
      for (int nt = 0; nt < 4; ++nt) {
        float p[4];
#pragma unroll
        for (int r = 0; r < 4; ++r) {
          int j = j0 + nt * 16 + lg * 4 + r;
          p[r] = (j < tq) ? __expf(s[nt][r] - m0) : 0.f;
          lsum[qs] += p[r];
        }
        unsigned int w0, w1;
        asm("v_cvt_pk_bf16_f32 %0, %1, %2" : "=v"(w0) : "v"(p[0]), "v"(p[1]));
        asm("v_cvt_pk_bf16_f32 %0, %1, %2" : "=v"(w1) : "v"(p[2]), "v"(p[3]));
        uint2 pk; pk.x = w0; pk.y = w1;
        *(uint2*)(pb + nt * 32 + lg * 8) = pk;
      }
#pragma unroll
      for (int ks = 0; ks < 2; ++ks) {
        short8 pf = *(const short8*)(pb + ks * 64 + lg * 16);
#pragma unroll
        for (int mt = 0; mt < 4; ++mt)
          accO[qs][mt] = __builtin_amdgcn_mfma_f32_16x16x32_bf16(vf[mt][ks], pf, accO[qs][mt], 0, 0, 0);
      }
    }
  }

  // epilogue: per-q denominator (reduce over lane groups), packed bf16 stores
#pragma unroll
  for (int qs = 0; qs < 2; ++qs) {
    float v = lsum[qs];
    v += __shfl_xor(v, 16, 64);
    v += __shfl_xor(v, 32, 64);
    float inv = 1.f / v;
    int tq = qstart + qs * 16 + q16;
    if (tq < T_) {
      unsigned short* yp = Yh + (size_t)tq * C_;
#pragma unroll
      for (int mt = 0; mt < 4; ++mt) {
        float o0 = accO[qs][mt][0] * inv, o1 = accO[qs][mt][1] * inv;
        float o2 = accO[qs][mt][2] * inv, o3 = accO[qs][mt][3] * inv;
        unsigned int u0, u1;
        asm("v_cvt_pk_bf16_f32 %0, %1, %2" : "=v"(u0) : "v"(o0), "v"(o1));
        asm("v_cvt_pk_bf16_f32 %0, %1, %2" : "=v"(u1) : "v"(o2), "v"(o3));
        uint2 pk; pk.x = u0; pk.y = u1;
        *(uint2*)(yp + mt * 16 + lg * 4) = pk;
      }
    }
  }
}

extern "C" void kernel_launch(void* const* d_in, const int* in_sizes, int n_in,
                              void* d_out, int out_size, void* d_ws, size_t ws_size,
                              hipStream_t stream) {
  const float* x          = (const float*)d_in[0];
  const float* W_la       = (const float*)d_in[1];
  const float* la_coef    = (const float*)d_in[2];
  const float* W_v        = (const float*)d_in[3];
  const float* v_coef     = (const float*)d_in[4];
  const float* kernel_bet = (const float*)d_in[5];
  const float* value_bet  = (const float*)d_in[6];
  const float* W_proj     = (const float*)d_in[7];
  float* out = (float*)d_out;

  float* ws = (float*)d_ws;
  const size_t NTOK = (size_t)B_ * T_ * C_;
  const size_t NSEGTOT = (size_t)B_ * NH * NSEG * HS;
  float* uxv     = ws;
  float* segend  = uxv + (size_t)B_ * T_ * CX;
  float* carryin = segend + NSEGTOT;
  __hip_bfloat16* kb16 = (__hip_bfloat16*)(carryin + NSEGTOT);
  __hip_bfloat16* vt16 = kb16 + NTOK;
  __hip_bfloat16* xb   = vt16 + NTOK;
  __hip_bfloat16* Wcat = xb + NTOK;
  __hip_bfloat16* Wpb  = Wcat + (size_t)CX * C_;
  __hip_bfloat16* yb   = xb;  // alias: xb dead after gemm1

  const int M = B_ * T_;

  cast_all<<<2048, 256, 0, stream>>>(x, W_la, W_v, W_proj, xb, Wcat, Wpb);

  gemm_bf16<<<dim3(M / 128, CX / 128), 256, 0, stream>>>(xb, Wcat, uxv, M, CX, C_);

  scan_a<<<dim3(B_ * NH * NSEG / 4), 256, 0, stream>>>(uxv, la_coef, segend);
  scan_b<<<dim3((B_ * NH * HS + 255) / 256), 256, 0, stream>>>(la_coef, segend, carryin);
  scan_c_norm<<<dim3(B_ * NH * NSEG / 4), 256, 0, stream>>>(la_coef, kernel_bet, carryin, uxv, kb16);

  vbuild_t<<<dim3(T_ / 64, B_ * NH), 256, 0, stream>>>(uxv, v_coef, value_bet, vt16);

  attn2<<<dim3(16, B_ * NH), 256, 0, stream>>>(kb16, vt16, kernel_bet, yb);

  gemm_bf16<<<dim3(M / 128, C_ / 128), 256, 0, stream>>>(yb, Wpb, out, M, C_, C_);
}

// Round 5
// 148.775 us; speedup vs baseline: 15.0045x; 1.0081x over previous
//
#include <hip/hip_runtime.h>
#include <hip/hip_bf16.h>
#include <math.h>

#define B_   2
#define T_   2048
#define C_   768
#define NH   12
#define HS   64
#define NSEG 64
#define SEGLEN 32
#define CX   1536   // uxv row stride (u | xv)

typedef __attribute__((ext_vector_type(8))) short short8;
typedef __attribute__((ext_vector_type(4))) short short4v;
typedef __attribute__((ext_vector_type(4))) float f32x4;

static __device__ inline unsigned short f2b(float f) {
  __hip_bfloat16 h = __float2bfloat16(f);
  unsigned short u;
  __builtin_memcpy(&u, &h, 2);
  return u;
}

#define GLOAD_LDS16(gp, lp)                                                        \
  __builtin_amdgcn_global_load_lds((const __attribute__((address_space(1))) void*)(gp), \
                                   (__attribute__((address_space(3))) void*)(lp), 16, 0, 0)

// ---------------- fused f32 -> bf16 casts (x, W_la|W_v -> Wcat, W_proj) -------------
__global__ __launch_bounds__(256) void cast_all(const float* __restrict__ x,
                                                const float* __restrict__ wla,
                                                const float* __restrict__ wv,
                                                const float* __restrict__ wp,
                                                __hip_bfloat16* __restrict__ xb,
                                                __hip_bfloat16* __restrict__ wcat,
                                                __hip_bfloat16* __restrict__ wpb) {
  const int NX4 = (B_ * T_ * C_) / 4;     // 786432
  const int NW4 = (C_ * C_) / 4;          // 147456
  const int TOT = NX4 + 3 * NW4;
  int i = blockIdx.x * 256 + threadIdx.x;
  int st = gridDim.x * 256;
  for (; i < TOT; i += st) {
    const float* s;
    unsigned short* d;
    if (i < NX4) { s = x + (size_t)i * 4; d = (unsigned short*)xb + (size_t)i * 4; }
    else if (i < NX4 + NW4) { int j = i - NX4; s = wla + (size_t)j * 4; d = (unsigned short*)wcat + (size_t)j * 4; }
    else if (i < NX4 + 2 * NW4) { int j = i - NX4 - NW4; s = wv + (size_t)j * 4; d = (unsigned short*)wcat + (size_t)(C_ * C_) + (size_t)j * 4; }
    else { int j = i - NX4 - 2 * NW4; s = wp + (size_t)j * 4; d = (unsigned short*)wpb + (size_t)j * 4; }
    float4 v = *(const float4*)s;
    short4v o;
    o.x = (short)f2b(v.x); o.y = (short)f2b(v.y); o.z = (short)f2b(v.z); o.w = (short)f2b(v.w);
    *(short4v*)d = o;
  }
}

// ---------------- bf16 MFMA GEMM: C[m,n] = sum_k A[m,k] * Bw[n,k], C f32 -------------
__global__ __launch_bounds__(256) void gemm_bf16(const __hip_bfloat16* __restrict__ A,
                                                 const __hip_bfloat16* __restrict__ Bw,
                                                 float* __restrict__ C,
                                                 int M, int N, int K) {
  __shared__ __hip_bfloat16 As[128 * 64];
  __shared__ __hip_bfloat16 Bs[128 * 64];
  const int tid = threadIdx.x;
  const int w = tid >> 6, lane = tid & 63;
  const int bm = blockIdx.x * 128, bn = blockIdx.y * 128;
  const int wr = w >> 1, wc = w & 1;

  f32x4 acc[4][4];
#pragma unroll
  for (int i = 0; i < 4; ++i)
#pragma unroll
    for (int j = 0; j < 4; ++j) acc[i][j] = (f32x4){0.f, 0.f, 0.f, 0.f};

  const int srow = (lane >> 3);
  const int soff0 = (lane & 7) * 16;
  const int sw = (lane & 7) << 4;

  for (int k0 = 0; k0 < K; k0 += 64) {
    __syncthreads();
#pragma unroll
    for (int c = 0; c < 8; ++c) {
      int gc = w * 8 + c;
      int isB = gc >> 4;
      int ci = gc & 15;
      int row = ci * 8 + srow;
      int soff = soff0 ^ ((row & 7) << 4);
      const __hip_bfloat16* gp =
          (isB ? Bw + (size_t)(bn + row) * K : A + (size_t)(bm + row) * K) + k0 + (soff >> 1);
      __hip_bfloat16* lp = (isB ? Bs : As) + ci * 512;
      GLOAD_LDS16(gp, lp);
    }
    __syncthreads();
#pragma unroll
    for (int ks = 0; ks < 2; ++ks) {
      short8 af[4], bf[4];
      const int colb = ks * 64 + (lane >> 4) * 16;
#pragma unroll
      for (int i = 0; i < 4; ++i) {
        int ra = wr * 64 + i * 16 + (lane & 15);
        int rb = wc * 64 + i * 16 + (lane & 15);
        af[i] = *(const short8*)((const char*)As + ra * 128 + (colb ^ sw));
        bf[i] = *(const short8*)((const char*)Bs + rb * 128 + (colb ^ sw));
      }
#pragma unroll
      for (int i = 0; i < 4; ++i)
#pragma unroll
        for (int j = 0; j < 4; ++j)
          acc[i][j] = __builtin_amdgcn_mfma_f32_16x16x32_bf16(af[i], bf[j], acc[i][j], 0, 0, 0);
    }
  }
#pragma unroll
  for (int i = 0; i < 4; ++i) {
#pragma unroll
    for (int r = 0; r < 4; ++r) {
      int m = bm + wr * 64 + i * 16 + (lane >> 4) * 4 + r;
      float* cp = C + (size_t)m * N + bn + wc * 64 + (lane & 15);
#pragma unroll
      for (int j = 0; j < 4; ++j) cp[j * 16] = acc[i][j][r];
    }
  }
}

// ---------------- Scan pass A: local leaky-average per segment, IN PLACE on u -------
__global__ __launch_bounds__(256) void scan_a(float* __restrict__ uxv,
                                              const float* __restrict__ la_coef,
                                              float* __restrict__ segend) {
  int cid = blockIdx.x * 4 + (threadIdx.x >> 6);  // bh*NSEG + seg
  int d   = threadIdx.x & 63;
  int seg = cid & (NSEG - 1);
  int bh  = cid >> 6;
  int h   = bh % NH;
  int b   = bh / NH;
  float c  = la_coef[h];
  float oc = 1.f - c;
  int t0 = seg * SEGLEN;
  float* up = uxv + ((size_t)b * T_ + t0) * CX + h * HS + d;
  float y = 0.f;
  for (int i = 0; i < SEGLEN; ++i) {
    float uv = up[(size_t)i * CX];
    y = fmaf(c, y, oc * uv);
    up[(size_t)i * CX] = y;
  }
  segend[(size_t)cid * HS + d] = y;
}

// ---------------- Scan pass B: sequential combine of segment carries ----------------
__global__ __launch_bounds__(256) void scan_b(const float* __restrict__ la_coef,
                                              const float* __restrict__ segend,
                                              float* __restrict__ carryin) {
  int s = blockIdx.x * 256 + threadIdx.x;  // (b,h,d)
  if (s >= B_ * NH * HS) return;
  int d  = s & 63;
  int bh = s >> 6;
  int h  = bh % NH;
  float c = la_coef[h];
  float cl = c;
#pragma unroll
  for (int i = 0; i < 5; ++i) cl *= cl;  // c^32
  float h0 = 0.f;
  for (int seg = 0; seg < NSEG; ++seg) {
    int cid = bh * NSEG + seg;
    carryin[(size_t)cid * HS + d] = h0;
    h0 = fmaf(cl, h0, segend[(size_t)cid * HS + d]);
  }
}

// ---------------- Scan pass C + k normalization, writes bf16 ------------------------
__global__ __launch_bounds__(256) void scan_c_norm(const float* __restrict__ la_coef,
                                                   const float* __restrict__ kernel_beta,
                                                   const float* __restrict__ carryin,
                                                   const float* __restrict__ uxv,
                                                   __hip_bfloat16* __restrict__ kb16) {
  int cid = blockIdx.x * 4 + (threadIdx.x >> 6);
  int d   = threadIdx.x & 63;
  int seg = cid & (NSEG - 1);
  int bh  = cid >> 6;
  int h   = bh % NH;
  int b   = bh / NH;
  float c  = la_coef[h];
  float bk = __expf(fminf(kernel_beta[h] * 10.f, 5.f));
  float hin = carryin[(size_t)cid * HS + d];
  int t0 = seg * SEGLEN;
  const float* kp = uxv + ((size_t)b * T_ + t0) * CX + h * HS + d;
  __hip_bfloat16* op = kb16 + ((size_t)bh * T_ + t0) * HS + d;
  float powc = c;
  for (int i = 0; i < SEGLEN; ++i) {
    float val = fmaf(powc, hin, kp[(size_t)i * CX]);
    powc *= c;
    float ss = val * val;
#pragma unroll
    for (int off = 1; off < 64; off <<= 1) ss += __shfl_xor(ss, off, 64);
    float scale = bk / (sqrtf(ss) + 1e-6f);
    op[(size_t)i * HS] = __float2bfloat16(val * scale);
  }
}

// ---------------- v build: shift-mix, normalize, scale; writes TRANSPOSED bf16 ------
__global__ __launch_bounds__(256) void vbuild_t(const float* __restrict__ uxv,
                                                const float* __restrict__ v_coef,
                                                const float* __restrict__ value_beta,
                                                __hip_bfloat16* __restrict__ vt) {
  __shared__ __hip_bfloat16 sm[64][73];
  int t0 = blockIdx.x * 64;
  int bh = blockIdx.y;
  int h = bh % NH, b = bh / NH;
  int w = threadIdx.x >> 6, lane = threadIdx.x & 63;
  float vc = v_coef[h];
  float vb = __expf(fminf(value_beta[h] * 10.f, 5.f));
  for (int i = 0; i < 16; ++i) {
    int tl = w * 16 + i;
    int t = t0 + tl;
    const float* xp = uxv + ((size_t)b * T_ + t) * CX + 768 + h * HS + lane;
    float x0 = *xp;
    float x1 = (t + 1 < T_) ? xp[CX] : 0.f;
    float vf = (1.f - vc) * x1 + vc * x0;
    float ss = vf * vf;
#pragma unroll
    for (int off = 1; off < 64; off <<= 1) ss += __shfl_xor(ss, off, 64);
    sm[tl][lane] = __float2bfloat16(vf * vb / (sqrtf(ss) + 1e-6f));
  }
  __syncthreads();
  int d = threadIdx.x >> 3;
  int c = threadIdx.x & 7;
  for (int i = 0; i < 2; ++i) {
    int dd = d + i * 32;
    short8 v;
#pragma unroll
    for (int k = 0; k < 8; ++k)
      v[k] = (short)((const unsigned short*)&sm[c * 8 + k][dd])[0];
    *(short8*)((unsigned short*)vt + ((size_t)bh * HS + dd) * T_ + t0 + c * 8) = v;
  }
}

// ---------------- attention v3: 8 waves, key-split halves, LDS partial combine ------
// Kg (B,NH,T,HS) bf16; Vtg (B,NH,HS,T) bf16; Y (B,T,C) bf16.
__global__ __launch_bounds__(512, 4) void attn3(const __hip_bfloat16* __restrict__ Kg,
                                                const __hip_bfloat16* __restrict__ Vtg,
                                                const float* __restrict__ kernel_beta,
                                                __hip_bfloat16* __restrict__ Y) {
  __shared__ char Pl[16][2304];   // per (wave,qset) P slice: 16 rows x 144B
  __shared__ f32x4 cbA[2048];     // half1 accO partials: [(wp*2+qs)*4+mt]*64+lane
  __shared__ float cbL[512];      // half1 lsum partials: (wp*2+qs)*64+lane
  const int bh = blockIdx.y;
  const int b = bh / NH, h = bh % NH;
  const int tid = threadIdx.x;
  const int w = tid >> 6, lane = tid & 63;
  const int wp = w & 3, half = w >> 2;
  const int q16 = lane & 15, lg = lane >> 4;
  const int i = blockIdx.x;  // 0..15
  // balanced chunk assignment: block total work is constant
  const int c = (wp == 0) ? i : (wp == 1) ? 31 - i : (wp == 2) ? 32 + i : 63 - i;
  const int qstart = 1 + c * 32;
  float bk = __expf(fminf(kernel_beta[h] * 10.f, 5.f));
  float m0 = bk * bk;
  const unsigned short* Kh = (const unsigned short*)Kg + (size_t)bh * T_ * HS;
  const unsigned short* Vh = (const unsigned short*)Vtg + (size_t)bh * HS * T_;
  unsigned short* Yh = (unsigned short*)Y + (size_t)b * T_ * C_ + h * HS;

  if (i == 0 && w == 0) Yh[lane] = 0;  // t=0 row zero

  // Q fragments (B-operand layout): lane holds q-col = q16, d contiguous
  short8 qf[2][2];
#pragma unroll
  for (int qs = 0; qs < 2; ++qs) {
    int tq = qstart + qs * 16 + q16;
    if (tq > T_ - 1) tq = T_ - 1;
#pragma unroll
    for (int ks = 0; ks < 2; ++ks)
      qf[qs][ks] = *(const short8*)(Kh + (size_t)tq * HS + ks * 32 + lg * 8);
  }

  f32x4 zero = {0.f, 0.f, 0.f, 0.f};
  f32x4 accO[2][4];
#pragma unroll
  for (int qs = 0; qs < 2; ++qs)
#pragma unroll
    for (int mt = 0; mt < 4; ++mt) accO[qs][mt] = zero;
  float lsum[2] = {0.f, 0.f};

  char* pb0 = &Pl[w * 2 + 0][0] + q16 * 144;
  char* pb1 = &Pl[w * 2 + 1][0] + q16 * 144;

  const int NTT = (qstart + 94) >> 6;
  const int NTH = NTT >> 1;
  const int ktlo = half ? NTH : 0;
  const int kthi = half ? NTT : NTH;
  for (int kt = ktlo; kt < kthi; ++kt) {
    const int j0 = kt * 64;
    short8 kf[4][2], vf[4][2];
#pragma unroll
    for (int nt = 0; nt < 4; ++nt)
#pragma unroll
      for (int ks = 0; ks < 2; ++ks) {
        kf[nt][ks] = *(const short8*)(Kh + (size_t)(j0 + nt * 16 + q16) * HS + ks * 32 + lg * 8);
        vf[nt][ks] = *(const short8*)(Vh + (size_t)(nt * 16 + q16) * T_ + j0 + ks * 32 + lg * 8);
      }
#pragma unroll
    for (int qs = 0; qs < 2; ++qs) {
      const int tq = qstart + qs * 16 + q16;
      char* pb = qs ? pb1 : pb0;
      f32x4 s[4];
#pragma unroll
      for (int nt = 0; nt < 4; ++nt) {
        s[nt] = __builtin_amdgcn_mfma_f32_16x16x32_bf16(kf[nt][0], qf[qs][0], zero, 0, 0, 0);
        s[nt] = __builtin_amdgcn_mfma_f32_16x16x32_bf16(kf[nt][1], qf[qs][1], s[nt], 0, 0, 0);
      }
#pragma unroll
      for (int nt = 0; nt < 4; ++nt) {
        float p[4];
#pragma unroll
        for (int r = 0; r < 4; ++r) {
          int j = j0 + nt * 16 + lg * 4 + r;
          p[r] = (j < tq) ? __expf(s[nt][r] - m0) : 0.f;
          lsum[qs] += p[r];
        }
        unsigned int w0, w1;
        asm("v_cvt_pk_bf16_f32 %0, %1, %2" : "=v"(w0) : "v"(p[0]), "v"(p[1]));
        asm("v_cvt_pk_bf16_f32 %0, %1, %2" : "=v"(w1) : "v"(p[2]), "v"(p[3]));
        uint2 pk; pk.x = w0; pk.y = w1;
        *(uint2*)(pb + nt * 32 + lg * 8) = pk;
      }
#pragma unroll
      for (int ks = 0; ks < 2; ++ks) {
        short8 pf = *(const short8*)(pb + ks * 64 + lg * 16);
#pragma unroll
        for (int mt = 0; mt < 4; ++mt)
          accO[qs][mt] = __builtin_amdgcn_mfma_f32_16x16x32_bf16(vf[mt][ks], pf, accO[qs][mt], 0, 0, 0);
      }
    }
  }

  // half1 -> LDS partials; half0 combines and stores
  if (half) {
#pragma unroll
    for (int qs = 0; qs < 2; ++qs) {
#pragma unroll
      for (int mt = 0; mt < 4; ++mt)
        cbA[((wp * 2 + qs) * 4 + mt) * 64 + lane] = accO[qs][mt];
      cbL[(wp * 2 + qs) * 64 + lane] = lsum[qs];
    }
  }
  __syncthreads();
  if (!half) {
#pragma unroll
    for (int qs = 0; qs < 2; ++qs) {
#pragma unroll
      for (int mt = 0; mt < 4; ++mt) {
        f32x4 o = cbA[((wp * 2 + qs) * 4 + mt) * 64 + lane];
        accO[qs][mt][0] += o[0]; accO[qs][mt][1] += o[1];
        accO[qs][mt][2] += o[2]; accO[qs][mt][3] += o[3];
      }
      lsum[qs] += cbL[(wp * 2 + qs) * 64 + lane];
    }
#pragma unroll
    for (int qs = 0; qs < 2; ++qs) {
      float v = lsum[qs];
      v += __shfl_xor(v, 16, 64);
      v += __shfl_xor(v, 32, 64);
      float inv = 1.f / v;
      int tq = qstart + qs * 16 + q16;
      if (tq < T_) {
        unsigned short* yp = Yh + (size_t)tq * C_;
#pragma unroll
        for (int mt = 0; mt < 4; ++mt) {
          float o0 = accO[qs][mt][0] * inv, o1 = accO[qs][mt][1] * inv;
          float o2 = accO[qs][mt][2] * inv, o3 = accO[qs][mt][3] * inv;
          unsigned int u0, u1;
          asm("v_cvt_pk_bf16_f32 %0, %1, %2" : "=v"(u0) : "v"(o0), "v"(o1));
          asm("v_cvt_pk_bf16_f32 %0, %1, %2" : "=v"(u1) : "v"(o2), "v"(o3));
          uint2 pk; pk.x = u0; pk.y = u1;
          *(uint2*)(yp + mt * 16 + lg * 4) = pk;
        }
      }
    }
  }
}

extern "C" void kernel_launch(void* const* d_in, const int* in_sizes, int n_in,
                              void* d_out, int out_size, void* d_ws, size_t ws_size,
                              hipStream_t stream) {
  const float* x          = (const float*)d_in[0];
  const float* W_la       = (const float*)d_in[1];
  const float* la_coef    = (const float*)d_in[2];
  const float* W_v        = (const float*)d_in[3];
  const float* v_coef     = (const float*)d_in[4];
  const float* kernel_bet = (const float*)d_in[5];
  const float* value_bet  = (const float*)d_in[6];
  const float* W_proj     = (const float*)d_in[7];
  float* out = (float*)d_out;

  float* ws = (float*)d_ws;
  const size_t NTOK = (size_t)B_ * T_ * C_;
  const size_t NSEGTOT = (size_t)B_ * NH * NSEG * HS;
  float* uxv     = ws;
  float* segend  = uxv + (size_t)B_ * T_ * CX;
  float* carryin = segend + NSEGTOT;
  __hip_bfloat16* kb16 = (__hip_bfloat16*)(carryin + NSEGTOT);
  __hip_bfloat16* vt16 = kb16 + NTOK;
  __hip_bfloat16* xb   = vt16 + NTOK;
  __hip_bfloat16* Wcat = xb + NTOK;
  __hip_bfloat16* Wpb  = Wcat + (size_t)CX * C_;
  __hip_bfloat16* yb   = xb;  // alias: xb dead after gemm1

  const int M = B_ * T_;

  cast_all<<<2048, 256, 0, stream>>>(x, W_la, W_v, W_proj, xb, Wcat, Wpb);

  gemm_bf16<<<dim3(M / 128, CX / 128), 256, 0, stream>>>(xb, Wcat, uxv, M, CX, C_);

  scan_a<<<dim3(B_ * NH * NSEG / 4), 256, 0, stream>>>(uxv, la_coef, segend);
  scan_b<<<dim3((B_ * NH * HS + 255) / 256), 256, 0, stream>>>(la_coef, segend, carryin);
  scan_c_norm<<<dim3(B_ * NH * NSEG / 4), 256, 0, stream>>>(la_coef, kernel_bet, carryin, uxv, kb16);

  vbuild_t<<<dim3(T_ / 64, B_ * NH), 256, 0, stream>>>(uxv, v_coef, value_bet, vt16);

  attn3<<<dim3(16, B_ * NH), 512, 0, stream>>>(kb16, vt16, kernel_bet, yb);

  gemm_bf16<<<dim3(M / 128, C_ / 128), 256, 0, stream>>>(yb, Wpb, out, M, C_, C_);
}

// Round 6
// 127.210 us; speedup vs baseline: 17.5481x; 1.1695x over previous
//
#include <hip/hip_runtime.h>
#include <hip/hip_bf16.h>
#include <math.h>

#define B_   2
#define T_   2048
#define C_   768
#define NH   12
#define HS   64
#define NSEG 64
#define SEGLEN 32
#define CX   1536   // uxv row stride (u | xv)

typedef __attribute__((ext_vector_type(8))) short short8;
typedef __attribute__((ext_vector_type(4))) short short4v;
typedef __attribute__((ext_vector_type(4))) float f32x4;

static __device__ inline unsigned short f2b(float f) {
  __hip_bfloat16 h = __float2bfloat16(f);
  unsigned short u;
  __builtin_memcpy(&u, &h, 2);
  return u;
}

#define GLOAD_LDS16(gp, lp)                                                        \
  __builtin_amdgcn_global_load_lds((const __attribute__((address_space(1))) void*)(gp), \
                                   (__attribute__((address_space(3))) void*)(lp), 16, 0, 0)

// ---------------- fused f32 -> bf16 casts (x, W_la|W_v -> Wcat, W_proj) -------------
__global__ __launch_bounds__(256) void cast_all(const float* __restrict__ x,
                                                const float* __restrict__ wla,
                                                const float* __restrict__ wv,
                                                const float* __restrict__ wp,
                                                __hip_bfloat16* __restrict__ xb,
                                                __hip_bfloat16* __restrict__ wcat,
                                                __hip_bfloat16* __restrict__ wpb) {
  const int NX4 = (B_ * T_ * C_) / 4;     // 786432
  const int NW4 = (C_ * C_) / 4;          // 147456
  const int TOT = NX4 + 3 * NW4;
  int i = blockIdx.x * 256 + threadIdx.x;
  int st = gridDim.x * 256;
  for (; i < TOT; i += st) {
    const float* s;
    unsigned short* d;
    if (i < NX4) { s = x + (size_t)i * 4; d = (unsigned short*)xb + (size_t)i * 4; }
    else if (i < NX4 + NW4) { int j = i - NX4; s = wla + (size_t)j * 4; d = (unsigned short*)wcat + (size_t)j * 4; }
    else if (i < NX4 + 2 * NW4) { int j = i - NX4 - NW4; s = wv + (size_t)j * 4; d = (unsigned short*)wcat + (size_t)(C_ * C_) + (size_t)j * 4; }
    else { int j = i - NX4 - 2 * NW4; s = wp + (size_t)j * 4; d = (unsigned short*)wpb + (size_t)j * 4; }
    float4 v = *(const float4*)s;
    short4v o;
    o.x = (short)f2b(v.x); o.y = (short)f2b(v.y); o.z = (short)f2b(v.z); o.w = (short)f2b(v.w);
    *(short4v*)d = o;
  }
}

// ---------------- bf16 MFMA GEMM: C[m,n] = sum_k A[m,k] * Bw[n,k], C f32 -------------
__global__ __launch_bounds__(256) void gemm_bf16(const __hip_bfloat16* __restrict__ A,
                                                 const __hip_bfloat16* __restrict__ Bw,
                                                 float* __restrict__ C,
                                                 int M, int N, int K) {
  __shared__ __hip_bfloat16 As[128 * 64];
  __shared__ __hip_bfloat16 Bs[128 * 64];
  const int tid = threadIdx.x;
  const int w = tid >> 6, lane = tid & 63;
  const int bm = blockIdx.x * 128, bn = blockIdx.y * 128;
  const int wr = w >> 1, wc = w & 1;

  f32x4 acc[4][4];
#pragma unroll
  for (int i = 0; i < 4; ++i)
#pragma unroll
    for (int j = 0; j < 4; ++j) acc[i][j] = (f32x4){0.f, 0.f, 0.f, 0.f};

  const int srow = (lane >> 3);
  const int soff0 = (lane & 7) * 16;
  const int sw = (lane & 7) << 4;

  for (int k0 = 0; k0 < K; k0 += 64) {
    __syncthreads();
#pragma unroll
    for (int c = 0; c < 8; ++c) {
      int gc = w * 8 + c;
      int isB = gc >> 4;
      int ci = gc & 15;
      int row = ci * 8 + srow;
      int soff = soff0 ^ ((row & 7) << 4);
      const __hip_bfloat16* gp =
          (isB ? Bw + (size_t)(bn + row) * K : A + (size_t)(bm + row) * K) + k0 + (soff >> 1);
      __hip_bfloat16* lp = (isB ? Bs : As) + ci * 512;
      GLOAD_LDS16(gp, lp);
    }
    __syncthreads();
#pragma unroll
    for (int ks = 0; ks < 2; ++ks) {
      short8 af[4], bf[4];
      const int colb = ks * 64 + (lane >> 4) * 16;
#pragma unroll
      for (int i = 0; i < 4; ++i) {
        int ra = wr * 64 + i * 16 + (lane & 15);
        int rb = wc * 64 + i * 16 + (lane & 15);
        af[i] = *(const short8*)((const char*)As + ra * 128 + (colb ^ sw));
        bf[i] = *(const short8*)((const char*)Bs + rb * 128 + (colb ^ sw));
      }
#pragma unroll
      for (int i = 0; i < 4; ++i)
#pragma unroll
        for (int j = 0; j < 4; ++j)
          acc[i][j] = __builtin_amdgcn_mfma_f32_16x16x32_bf16(af[i], bf[j], acc[i][j], 0, 0, 0);
    }
  }
#pragma unroll
  for (int i = 0; i < 4; ++i) {
#pragma unroll
    for (int r = 0; r < 4; ++r) {
      int m = bm + wr * 64 + i * 16 + (lane >> 4) * 4 + r;
      float* cp = C + (size_t)m * N + bn + wc * 64 + (lane & 15);
#pragma unroll
      for (int j = 0; j < 4; ++j) cp[j * 16] = acc[i][j][r];
    }
  }
}

// ---------------- Scan pass A: local leaky-average per segment, IN PLACE on u -------
__global__ __launch_bounds__(256) void scan_a(float* __restrict__ uxv,
                                              const float* __restrict__ la_coef,
                                              float* __restrict__ segend) {
  int cid = blockIdx.x * 4 + (threadIdx.x >> 6);  // bh*NSEG + seg
  int d   = threadIdx.x & 63;
  int seg = cid & (NSEG - 1);
  int bh  = cid >> 6;
  int h   = bh % NH;
  int b   = bh / NH;
  float c  = la_coef[h];
  float oc = 1.f - c;
  int t0 = seg * SEGLEN;
  float* up = uxv + ((size_t)b * T_ + t0) * CX + h * HS + d;
  float y = 0.f;
  for (int i = 0; i < SEGLEN; ++i) {
    float uv = up[(size_t)i * CX];
    y = fmaf(c, y, oc * uv);
    up[(size_t)i * CX] = y;
  }
  segend[(size_t)cid * HS + d] = y;
}

// ---------------- Scan pass B: sequential combine of segment carries ----------------
__global__ __launch_bounds__(256) void scan_b(const float* __restrict__ la_coef,
                                              const float* __restrict__ segend,
                                              float* __restrict__ carryin) {
  int s = blockIdx.x * 256 + threadIdx.x;  // (b,h,d)
  if (s >= B_ * NH * HS) return;
  int d  = s & 63;
  int bh = s >> 6;
  int h  = bh % NH;
  float c = la_coef[h];
  float cl = c;
#pragma unroll
  for (int i = 0; i < 5; ++i) cl *= cl;  // c^32
  float h0 = 0.f;
  for (int seg = 0; seg < NSEG; ++seg) {
    int cid = bh * NSEG + seg;
    carryin[(size_t)cid * HS + d] = h0;
    h0 = fmaf(cl, h0, segend[(size_t)cid * HS + d]);
  }
}

// ---------------- Scan pass C + k normalization, writes bf16 ------------------------
__global__ __launch_bounds__(256) void scan_c_norm(const float* __restrict__ la_coef,
                                                   const float* __restrict__ kernel_beta,
                                                   const float* __restrict__ carryin,
                                                   const float* __restrict__ uxv,
                                                   __hip_bfloat16* __restrict__ kb16) {
  int cid = blockIdx.x * 4 + (threadIdx.x >> 6);
  int d   = threadIdx.x & 63;
  int seg = cid & (NSEG - 1);
  int bh  = cid >> 6;
  int h   = bh % NH;
  int b   = bh / NH;
  float c  = la_coef[h];
  float bk = __expf(fminf(kernel_beta[h] * 10.f, 5.f));
  float hin = carryin[(size_t)cid * HS + d];
  int t0 = seg * SEGLEN;
  const float* kp = uxv + ((size_t)b * T_ + t0) * CX + h * HS + d;
  __hip_bfloat16* op = kb16 + ((size_t)bh * T_ + t0) * HS + d;
  float powc = c;
  for (int i = 0; i < SEGLEN; ++i) {
    float val = fmaf(powc, hin, kp[(size_t)i * CX]);
    powc *= c;
    float ss = val * val;
#pragma unroll
    for (int off = 1; off < 64; off <<= 1) ss += __shfl_xor(ss, off, 64);
    float scale = bk / (sqrtf(ss) + 1e-6f);
    op[(size_t)i * HS] = __float2bfloat16(val * scale);
  }
}

// ---------------- v build: shift-mix, normalize, scale; writes TRANSPOSED bf16 ------
__global__ __launch_bounds__(256) void vbuild_t(const float* __restrict__ uxv,
                                                const float* __restrict__ v_coef,
                                                const float* __restrict__ value_beta,
                                                __hip_bfloat16* __restrict__ vt) {
  __shared__ __hip_bfloat16 sm[64][73];
  int t0 = blockIdx.x * 64;
  int bh = blockIdx.y;
  int h = bh % NH, b = bh / NH;
  int w = threadIdx.x >> 6, lane = threadIdx.x & 63;
  float vc = v_coef[h];
  float vb = __expf(fminf(value_beta[h] * 10.f, 5.f));
  for (int i = 0; i < 16; ++i) {
    int tl = w * 16 + i;
    int t = t0 + tl;
    const float* xp = uxv + ((size_t)b * T_ + t) * CX + 768 + h * HS + lane;
    float x0 = *xp;
    float x1 = (t + 1 < T_) ? xp[CX] : 0.f;
    float vf = (1.f - vc) * x1 + vc * x0;
    float ss = vf * vf;
#pragma unroll
    for (int off = 1; off < 64; off <<= 1) ss += __shfl_xor(ss, off, 64);
    sm[tl][lane] = __float2bfloat16(vf * vb / (sqrtf(ss) + 1e-6f));
  }
  __syncthreads();
  int d = threadIdx.x >> 3;
  int c = threadIdx.x & 7;
  for (int i = 0; i < 2; ++i) {
    int dd = d + i * 32;
    short8 v;
#pragma unroll
    for (int k = 0; k < 8; ++k)
      v[k] = (short)((const unsigned short*)&sm[c * 8 + k][dd])[0];
    *(short8*)((unsigned short*)vt + ((size_t)bh * HS + dd) * T_ + t0 + c * 8) = v;
  }
}

// ---------------- attention v4: LDS-staged K/V shared by 4 waves, XCD-local grid ----
// Kg (B,NH,T,HS) bf16; Vtg (B,NH,HS,T) bf16; Y (B,T,C) bf16.
// grid = (24 bh, 16 qtiles): all q-blocks of one bh land on the same XCD (24*qt % 8 == 0).
__global__ __launch_bounds__(256, 3) void attn4(const __hip_bfloat16* __restrict__ Kg,
                                                const __hip_bfloat16* __restrict__ Vtg,
                                                const float* __restrict__ kernel_beta,
                                                __hip_bfloat16* __restrict__ Y) {
  __shared__ __hip_bfloat16 Kt[2][64 * 64];   // [buf][row*64+col], staged swizzled
  __shared__ __hip_bfloat16 Vt[2][64 * 64];   // rows = d
  __shared__ char Pl[8][2304];                // per (wave,qset) P slice: 16 rows x 144B
  const int bh = blockIdx.x;
  const int b = bh / NH, h = bh % NH;
  const int w = threadIdx.x >> 6, lane = threadIdx.x & 63;
  const int q16 = lane & 15, lg = lane >> 4;
  const int it = 15 - blockIdx.y;            // heavy-first
  const int qb0 = 1 + it * 128;
  const int qstart = qb0 + w * 32;           // this wave's 32 q-rows
  float bk = __expf(fminf(kernel_beta[h] * 10.f, 5.f));
  float m0 = bk * bk;
  const unsigned short* Kh = (const unsigned short*)Kg + (size_t)bh * T_ * HS;
  const unsigned short* Vh = (const unsigned short*)Vtg + (size_t)bh * HS * T_;
  unsigned short* Yh = (unsigned short*)Y + (size_t)b * T_ * C_ + h * HS;

  if (it == 0 && w == 0) Yh[lane] = 0;  // t=0 row zero

  // Q fragments (B-operand): lane holds q-col = q16, d contiguous. One-time global read.
  short8 qf[2][2];
#pragma unroll
  for (int qs = 0; qs < 2; ++qs) {
    int tq = qstart + qs * 16 + q16;
    if (tq > T_ - 1) tq = T_ - 1;
#pragma unroll
    for (int ks = 0; ks < 2; ++ks)
      qf[qs][ks] = *(const short8*)(Kh + (size_t)tq * HS + ks * 32 + lg * 8);
  }

  f32x4 zero = {0.f, 0.f, 0.f, 0.f};
  f32x4 accO[2][4];
#pragma unroll
  for (int qs = 0; qs < 2; ++qs)
#pragma unroll
    for (int mt = 0; mt < 4; ++mt) accO[qs][mt] = zero;
  float lsum[2] = {0.f, 0.f};

  char* pb0 = &Pl[w * 2 + 0][0] + q16 * 144;
  char* pb1 = &Pl[w * 2 + 1][0] + q16 * 144;
  const int swr = (q16 & 7) << 4;  // read-side XOR swizzle (row&7)<<4, row = nt*16+q16

  // staging geometry: per buffer, K tile = 8 chunks of 8 rows x 128B; same for V.
  const int srow = lane >> 3;                       // 0..7
  const int soff = ((lane & 7) << 4) ^ (srow << 4); // inverse-swizzled source byte col

  const int NT = (qb0 + 190) >> 6;  // tiles covering keys j <= qb0+126

#define STAGE_KV(buf, j0)                                                             \
  {                                                                                   \
    _Pragma("unroll")                                                                 \
    for (int n = 0; n < 2; ++n) {                                                     \
      int ch = w * 2 + n;                                                             \
      int row = ch * 8 + srow;                                                        \
      GLOAD_LDS16((const char*)(Kh + (size_t)((j0) + row) * HS) + soff,               \
                  &Kt[buf][ch * 512]);                                                \
      GLOAD_LDS16((const char*)(Vh + (size_t)row * T_ + (j0)) + soff,                 \
                  &Vt[buf][ch * 512]);                                                \
    }                                                                                 \
  }

  STAGE_KV(0, 0);
  asm volatile("s_waitcnt vmcnt(0)" ::: "memory");
  __syncthreads();

  for (int kt = 0; kt < NT; ++kt) {
    const int cur = kt & 1;
    const int j0 = kt * 64;
    if (kt + 1 < NT) STAGE_KV(cur ^ 1, j0 + 64);

    const char* Kb = (const char*)&Kt[cur][0];
    const char* Vb = (const char*)&Vt[cur][0];
    short8 kf[4][2], vf[4][2];
#pragma unroll
    for (int nt = 0; nt < 4; ++nt)
#pragma unroll
      for (int ks = 0; ks < 2; ++ks) {
        const int colb = ks * 64 + lg * 16;
        kf[nt][ks] = *(const short8*)(Kb + (nt * 16 + q16) * 128 + (colb ^ swr));
        vf[nt][ks] = *(const short8*)(Vb + (nt * 16 + q16) * 128 + (colb ^ swr));
      }
#pragma unroll
    for (int qs = 0; qs < 2; ++qs) {
      const int tq = qstart + qs * 16 + q16;
      char* pb = qs ? pb1 : pb0;
      f32x4 s[4];
#pragma unroll
      for (int nt = 0; nt < 4; ++nt) {
        s[nt] = __builtin_amdgcn_mfma_f32_16x16x32_bf16(kf[nt][0], qf[qs][0], zero, 0, 0, 0);
        s[nt] = __builtin_amdgcn_mfma_f32_16x16x32_bf16(kf[nt][1], qf[qs][1], s[nt], 0, 0, 0);
      }
#pragma unroll
      for (int nt = 0; nt < 4; ++nt) {
        float p[4];
#pragma unroll
        for (int r = 0; r < 4; ++r) {
          int j = j0 + nt * 16 + lg * 4 + r;
          p[r] = (j < tq) ? __expf(s[nt][r] - m0) : 0.f;
          lsum[qs] += p[r];
        }
        unsigned int w0, w1;
        asm("v_cvt_pk_bf16_f32 %0, %1, %2" : "=v"(w0) : "v"(p[0]), "v"(p[1]));
        asm("v_cvt_pk_bf16_f32 %0, %1, %2" : "=v"(w1) : "v"(p[2]), "v"(p[3]));
        uint2 pk; pk.x = w0; pk.y = w1;
        *(uint2*)(pb + nt * 32 + lg * 8) = pk;
      }
#pragma unroll
      for (int ks = 0; ks < 2; ++ks) {
        short8 pf = *(const short8*)(pb + ks * 64 + lg * 16);
#pragma unroll
        for (int mt = 0; mt < 4; ++mt)
          accO[qs][mt] = __builtin_amdgcn_mfma_f32_16x16x32_bf16(vf[mt][ks], pf, accO[qs][mt], 0, 0, 0);
      }
    }
    asm volatile("s_waitcnt vmcnt(0)" ::: "memory");
    __syncthreads();
  }

  // epilogue: per-q denominator, packed bf16 stores
#pragma unroll
  for (int qs = 0; qs < 2; ++qs) {
    float v = lsum[qs];
    v += __shfl_xor(v, 16, 64);
    v += __shfl_xor(v, 32, 64);
    float inv = 1.f / v;
    int tq = qstart + qs * 16 + q16;
    if (tq < T_) {
      unsigned short* yp = Yh + (size_t)tq * C_;
#pragma unroll
      for (int mt = 0; mt < 4; ++mt) {
        float o0 = accO[qs][mt][0] * inv, o1 = accO[qs][mt][1] * inv;
        float o2 = accO[qs][mt][2] * inv, o3 = accO[qs][mt][3] * inv;
        unsigned int u0, u1;
        asm("v_cvt_pk_bf16_f32 %0, %1, %2" : "=v"(u0) : "v"(o0), "v"(o1));
        asm("v_cvt_pk_bf16_f32 %0, %1, %2" : "=v"(u1) : "v"(o2), "v"(o3));
        uint2 pk; pk.x = u0; pk.y = u1;
        *(uint2*)(yp + mt * 16 + lg * 4) = pk;
      }
    }
  }
#undef STAGE_KV
}

extern "C" void kernel_launch(void* const* d_in, const int* in_sizes, int n_in,
                              void* d_out, int out_size, void* d_ws, size_t ws_size,
                              hipStream_t stream) {
  const float* x          = (const float*)d_in[0];
  const float* W_la       = (const float*)d_in[1];
  const float* la_coef    = (const float*)d_in[2];
  const float* W_v        = (const float*)d_in[3];
  const float* v_coef     = (const float*)d_in[4];
  const float* kernel_bet = (const float*)d_in[5];
  const float* value_bet  = (const float*)d_in[6];
  const float* W_proj     = (const float*)d_in[7];
  float* out = (float*)d_out;

  float* ws = (float*)d_ws;
  const size_t NTOK = (size_t)B_ * T_ * C_;
  const size_t NSEGTOT = (size_t)B_ * NH * NSEG * HS;
  float* uxv     = ws;
  float* segend  = uxv + (size_t)B_ * T_ * CX;
  float* carryin = segend + NSEGTOT;
  __hip_bfloat16* kb16 = (__hip_bfloat16*)(carryin + NSEGTOT);
  __hip_bfloat16* vt16 = kb16 + NTOK;
  __hip_bfloat16* xb   = vt16 + NTOK;
  __hip_bfloat16* Wcat = xb + NTOK;
  __hip_bfloat16* Wpb  = Wcat + (size_t)CX * C_;
  __hip_bfloat16* yb   = xb;  // alias: xb dead after gemm1

  const int M = B_ * T_;

  cast_all<<<2048, 256, 0, stream>>>(x, W_la, W_v, W_proj, xb, Wcat, Wpb);

  gemm_bf16<<<dim3(M / 128, CX / 128), 256, 0, stream>>>(xb, Wcat, uxv, M, CX, C_);

  scan_a<<<dim3(B_ * NH * NSEG / 4), 256, 0, stream>>>(uxv, la_coef, segend);
  scan_b<<<dim3((B_ * NH * HS + 255) / 256), 256, 0, stream>>>(la_coef, segend, carryin);
  scan_c_norm<<<dim3(B_ * NH * NSEG / 4), 256, 0, stream>>>(la_coef, kernel_bet, carryin, uxv, kb16);

  vbuild_t<<<dim3(T_ / 64, B_ * NH), 256, 0, stream>>>(uxv, v_coef, value_bet, vt16);

  attn4<<<dim3(B_ * NH, 16), 256, 0, stream>>>(kb16, vt16, kernel_bet, yb);

  gemm_bf16<<<dim3(M / 128, C_ / 128), 256, 0, stream>>>(yb, Wpb, out, M, C_, C_);
}

// Round 7
// 114.089 us; speedup vs baseline: 19.5663x; 1.1150x over previous
//
#include <hip/hip_runtime.h>
#include <hip/hip_bf16.h>
#include <math.h>

#define B_   2
#define T_   2048
#define C_   768
#define NH   12
#define HS   64
#define NSEG 64
#define SEGLEN 32
#define CX   1536   // uxv row stride (u | xv)

typedef __attribute__((ext_vector_type(8))) short short8;
typedef __attribute__((ext_vector_type(4))) short short4v;
typedef __attribute__((ext_vector_type(4))) float f32x4;

static __device__ inline unsigned short f2b(float f) {
  __hip_bfloat16 h = __float2bfloat16(f);
  unsigned short u;
  __builtin_memcpy(&u, &h, 2);
  return u;
}

#define GLOAD_LDS16(gp, lp)                                                        \
  __builtin_amdgcn_global_load_lds((const __attribute__((address_space(1))) void*)(gp), \
                                   (__attribute__((address_space(3))) void*)(lp), 16, 0, 0)

// ---------------- fused f32 -> bf16 casts (x, W_la|W_v -> Wcat, W_proj) -------------
__global__ __launch_bounds__(256) void cast_all(const float* __restrict__ x,
                                                const float* __restrict__ wla,
                                                const float* __restrict__ wv,
                                                const float* __restrict__ wp,
                                                __hip_bfloat16* __restrict__ xb,
                                                __hip_bfloat16* __restrict__ wcat,
                                                __hip_bfloat16* __restrict__ wpb) {
  const int NX4 = (B_ * T_ * C_) / 4;     // 786432
  const int NW4 = (C_ * C_) / 4;          // 147456
  const int TOT = NX4 + 3 * NW4;
  int i = blockIdx.x * 256 + threadIdx.x;
  int st = gridDim.x * 256;
  for (; i < TOT; i += st) {
    const float* s;
    unsigned short* d;
    if (i < NX4) { s = x + (size_t)i * 4; d = (unsigned short*)xb + (size_t)i * 4; }
    else if (i < NX4 + NW4) { int j = i - NX4; s = wla + (size_t)j * 4; d = (unsigned short*)wcat + (size_t)j * 4; }
    else if (i < NX4 + 2 * NW4) { int j = i - NX4 - NW4; s = wv + (size_t)j * 4; d = (unsigned short*)wcat + (size_t)(C_ * C_) + (size_t)j * 4; }
    else { int j = i - NX4 - 2 * NW4; s = wp + (size_t)j * 4; d = (unsigned short*)wpb + (size_t)j * 4; }
    float4 v = *(const float4*)s;
    short4v o;
    o.x = (short)f2b(v.x); o.y = (short)f2b(v.y); o.z = (short)f2b(v.z); o.w = (short)f2b(v.w);
    *(short4v*)d = o;
  }
}

// ---------------- bf16 MFMA GEMM: C[m,n] = sum_k A[m,k] * Bw[n,k], C f32 -------------
__global__ __launch_bounds__(256) void gemm_bf16(const __hip_bfloat16* __restrict__ A,
                                                 const __hip_bfloat16* __restrict__ Bw,
                                                 float* __restrict__ C,
                                                 int M, int N, int K) {
  __shared__ __hip_bfloat16 As[128 * 64];
  __shared__ __hip_bfloat16 Bs[128 * 64];
  const int tid = threadIdx.x;
  const int w = tid >> 6, lane = tid & 63;
  const int bm = blockIdx.x * 128, bn = blockIdx.y * 128;
  const int wr = w >> 1, wc = w & 1;

  f32x4 acc[4][4];
#pragma unroll
  for (int i = 0; i < 4; ++i)
#pragma unroll
    for (int j = 0; j < 4; ++j) acc[i][j] = (f32x4){0.f, 0.f, 0.f, 0.f};

  const int srow = (lane >> 3);
  const int soff0 = (lane & 7) * 16;
  const int sw = (lane & 7) << 4;

  for (int k0 = 0; k0 < K; k0 += 64) {
    __syncthreads();
#pragma unroll
    for (int c = 0; c < 8; ++c) {
      int gc = w * 8 + c;
      int isB = gc >> 4;
      int ci = gc & 15;
      int row = ci * 8 + srow;
      int soff = soff0 ^ ((row & 7) << 4);
      const __hip_bfloat16* gp =
          (isB ? Bw + (size_t)(bn + row) * K : A + (size_t)(bm + row) * K) + k0 + (soff >> 1);
      __hip_bfloat16* lp = (isB ? Bs : As) + ci * 512;
      GLOAD_LDS16(gp, lp);
    }
    __syncthreads();
#pragma unroll
    for (int ks = 0; ks < 2; ++ks) {
      short8 af[4], bf[4];
      const int colb = ks * 64 + (lane >> 4) * 16;
#pragma unroll
      for (int i = 0; i < 4; ++i) {
        int ra = wr * 64 + i * 16 + (lane & 15);
        int rb = wc * 64 + i * 16 + (lane & 15);
        af[i] = *(const short8*)((const char*)As + ra * 128 + (colb ^ sw));
        bf[i] = *(const short8*)((const char*)Bs + rb * 128 + (colb ^ sw));
      }
#pragma unroll
      for (int i = 0; i < 4; ++i)
#pragma unroll
        for (int j = 0; j < 4; ++j)
          acc[i][j] = __builtin_amdgcn_mfma_f32_16x16x32_bf16(af[i], bf[j], acc[i][j], 0, 0, 0);
    }
  }
#pragma unroll
  for (int i = 0; i < 4; ++i) {
#pragma unroll
    for (int r = 0; r < 4; ++r) {
      int m = bm + wr * 64 + i * 16 + (lane >> 4) * 4 + r;
      float* cp = C + (size_t)m * N + bn + wc * 64 + (lane & 15);
#pragma unroll
      for (int j = 0; j < 4; ++j) cp[j * 16] = acc[i][j][r];
    }
  }
}

// ---------------- Scan pass A: local leaky-average per segment, IN PLACE on u -------
__global__ __launch_bounds__(256) void scan_a(float* __restrict__ uxv,
                                              const float* __restrict__ la_coef,
                                              float* __restrict__ segend) {
  int cid = blockIdx.x * 4 + (threadIdx.x >> 6);  // bh*NSEG + seg
  int d   = threadIdx.x & 63;
  int seg = cid & (NSEG - 1);
  int bh  = cid >> 6;
  int h   = bh % NH;
  int b   = bh / NH;
  float c  = la_coef[h];
  float oc = 1.f - c;
  int t0 = seg * SEGLEN;
  float* up = uxv + ((size_t)b * T_ + t0) * CX + h * HS + d;
  float y = 0.f;
  for (int i = 0; i < SEGLEN; ++i) {
    float uv = up[(size_t)i * CX];
    y = fmaf(c, y, oc * uv);
    up[(size_t)i * CX] = y;
  }
  segend[(size_t)cid * HS + d] = y;
}

// ---------------- Scan pass B: sequential combine of segment carries ----------------
__global__ __launch_bounds__(256) void scan_b(const float* __restrict__ la_coef,
                                              const float* __restrict__ segend,
                                              float* __restrict__ carryin) {
  int s = blockIdx.x * 256 + threadIdx.x;  // (b,h,d)
  if (s >= B_ * NH * HS) return;
  int d  = s & 63;
  int bh = s >> 6;
  int h  = bh % NH;
  float c = la_coef[h];
  float cl = c;
#pragma unroll
  for (int i = 0; i < 5; ++i) cl *= cl;  // c^32
  float h0 = 0.f;
  for (int seg = 0; seg < NSEG; ++seg) {
    int cid = bh * NSEG + seg;
    carryin[(size_t)cid * HS + d] = h0;
    h0 = fmaf(cl, h0, segend[(size_t)cid * HS + d]);
  }
}

// ---------------- Scan pass C + k normalization, writes bf16 ------------------------
__global__ __launch_bounds__(256) void scan_c_norm(const float* __restrict__ la_coef,
                                                   const float* __restrict__ kernel_beta,
                                                   const float* __restrict__ carryin,
                                                   const float* __restrict__ uxv,
                                                   __hip_bfloat16* __restrict__ kb16) {
  int cid = blockIdx.x * 4 + (threadIdx.x >> 6);
  int d   = threadIdx.x & 63;
  int seg = cid & (NSEG - 1);
  int bh  = cid >> 6;
  int h   = bh % NH;
  int b   = bh / NH;
  float c  = la_coef[h];
  float bk = __expf(fminf(kernel_beta[h] * 10.f, 5.f));
  float hin = carryin[(size_t)cid * HS + d];
  int t0 = seg * SEGLEN;
  const float* kp = uxv + ((size_t)b * T_ + t0) * CX + h * HS + d;
  __hip_bfloat16* op = kb16 + ((size_t)bh * T_ + t0) * HS + d;
  float powc = c;
  for (int i = 0; i < SEGLEN; ++i) {
    float val = fmaf(powc, hin, kp[(size_t)i * CX]);
    powc *= c;
    float ss = val * val;
#pragma unroll
    for (int off = 1; off < 64; off <<= 1) ss += __shfl_xor(ss, off, 64);
    float scale = bk / (sqrtf(ss) + 1e-6f);
    op[(size_t)i * HS] = __float2bfloat16(val * scale);
  }
}

// ---------------- v build: shift-mix, normalize, scale; writes TRANSPOSED bf16 ------
__global__ __launch_bounds__(256) void vbuild_t(const float* __restrict__ uxv,
                                                const float* __restrict__ v_coef,
                                                const float* __restrict__ value_beta,
                                                __hip_bfloat16* __restrict__ vt) {
  __shared__ __hip_bfloat16 sm[64][73];
  int t0 = blockIdx.x * 64;
  int bh = blockIdx.y;
  int h = bh % NH, b = bh / NH;
  int w = threadIdx.x >> 6, lane = threadIdx.x & 63;
  float vc = v_coef[h];
  float vb = __expf(fminf(value_beta[h] * 10.f, 5.f));
  for (int i = 0; i < 16; ++i) {
    int tl = w * 16 + i;
    int t = t0 + tl;
    const float* xp = uxv + ((size_t)b * T_ + t) * CX + 768 + h * HS + lane;
    float x0 = *xp;
    float x1 = (t + 1 < T_) ? xp[CX] : 0.f;
    float vf = (1.f - vc) * x1 + vc * x0;
    float ss = vf * vf;
#pragma unroll
    for (int off = 1; off < 64; off <<= 1) ss += __shfl_xor(ss, off, 64);
    sm[tl][lane] = __float2bfloat16(vf * vb / (sqrtf(ss) + 1e-6f));
  }
  __syncthreads();
  int d = threadIdx.x >> 3;
  int c = threadIdx.x & 7;
  for (int i = 0; i < 2; ++i) {
    int dd = d + i * 32;
    short8 v;
#pragma unroll
    for (int k = 0; k < 8; ++k)
      v[k] = (short)((const unsigned short*)&sm[c * 8 + k][dd])[0];
    *(short8*)((unsigned short*)vt + ((size_t)bh * HS + dd) * T_ + t0 + c * 8) = v;
  }
}

// ---------------- attention v5: 64-q blocks, 3 blocks/CU, XCD-local grid -------------
// Kg (B,NH,T,HS) bf16; Vtg (B,NH,HS,T) bf16; Y (B,T,C) bf16.
// grid = (24 bh, 32 qtiles): all q-blocks of one bh land on the same XCD (24 % 8 == 0).
__global__ __launch_bounds__(256, 3) void attn5(const __hip_bfloat16* __restrict__ Kg,
                                                const __hip_bfloat16* __restrict__ Vtg,
                                                const float* __restrict__ kernel_beta,
                                                __hip_bfloat16* __restrict__ Y) {
  __shared__ __hip_bfloat16 Kt[2][64 * 64];   // [buf][row*64+col], staged swizzled
  __shared__ __hip_bfloat16 Vt[2][64 * 64];   // rows = d
  __shared__ char Pl[4][2304];                // per-wave P slice: 16 rows x 144B
  const int bh = blockIdx.x;
  const int b = bh / NH, h = bh % NH;
  const int w = threadIdx.x >> 6, lane = threadIdx.x & 63;
  const int q16 = lane & 15, lg = lane >> 4;
  const int it = 31 - blockIdx.y;            // heavy-first
  const int qb0 = 1 + it * 64;
  float bk = __expf(fminf(kernel_beta[h] * 10.f, 5.f));
  float m0 = bk * bk;
  const unsigned short* Kh = (const unsigned short*)Kg + (size_t)bh * T_ * HS;
  const unsigned short* Vh = (const unsigned short*)Vtg + (size_t)bh * HS * T_;
  unsigned short* Yh = (unsigned short*)Y + (size_t)b * T_ * C_ + h * HS;

  if (it == 0 && w == 0) Yh[lane] = 0;  // t=0 row zero

  // this wave's 16 q rows; Q fragment (B-operand): lane holds q-col = q16
  const int tq = qb0 + w * 16 + q16;
  short8 qf[2];
  {
    int tqc = tq > T_ - 1 ? T_ - 1 : tq;
#pragma unroll
    for (int ks = 0; ks < 2; ++ks)
      qf[ks] = *(const short8*)(Kh + (size_t)tqc * HS + ks * 32 + lg * 8);
  }

  f32x4 zero = {0.f, 0.f, 0.f, 0.f};
  f32x4 accO[4];
#pragma unroll
  for (int mt = 0; mt < 4; ++mt) accO[mt] = zero;
  float lsum = 0.f;

  char* pb = &Pl[w][0] + q16 * 144;
  const int swr = (q16 & 7) << 4;  // read-side XOR swizzle (row&7)<<4, row = nt*16+q16

  // staging geometry: per buffer, K tile = 8 chunks of 8 rows x 128B; same for V.
  const int srow = lane >> 3;                       // 0..7
  const int soff = ((lane & 7) << 4) ^ (srow << 4); // inverse-swizzled source byte col

  const int NT = (qb0 + 126) >> 6;  // tiles covering keys j <= qb0+62

#define STAGE_KV(buf, j0)                                                             \
  {                                                                                   \
    _Pragma("unroll")                                                                 \
    for (int n = 0; n < 2; ++n) {                                                     \
      int ch = w * 2 + n;                                                             \
      int row = ch * 8 + srow;                                                        \
      GLOAD_LDS16((const char*)(Kh + (size_t)((j0) + row) * HS) + soff,               \
                  &Kt[buf][ch * 512]);                                                \
      GLOAD_LDS16((const char*)(Vh + (size_t)row * T_ + (j0)) + soff,                 \
                  &Vt[buf][ch * 512]);                                                \
    }                                                                                 \
  }

  STAGE_KV(0, 0);
  asm volatile("s_waitcnt vmcnt(0)" ::: "memory");
  __syncthreads();

  for (int kt = 0; kt < NT; ++kt) {
    const int cur = kt & 1;
    const int j0 = kt * 64;
    if (kt + 1 < NT) STAGE_KV(cur ^ 1, j0 + 64);

    const char* Kb = (const char*)&Kt[cur][0];
    const char* Vb = (const char*)&Vt[cur][0];
    short8 kf[4][2], vf[4][2];
#pragma unroll
    for (int nt = 0; nt < 4; ++nt)
#pragma unroll
      for (int ks = 0; ks < 2; ++ks) {
        const int colb = ks * 64 + lg * 16;
        kf[nt][ks] = *(const short8*)(Kb + (nt * 16 + q16) * 128 + (colb ^ swr));
        vf[nt][ks] = *(const short8*)(Vb + (nt * 16 + q16) * 128 + (colb ^ swr));
      }
    f32x4 s[4];
#pragma unroll
    for (int nt = 0; nt < 4; ++nt) {
      s[nt] = __builtin_amdgcn_mfma_f32_16x16x32_bf16(kf[nt][0], qf[0], zero, 0, 0, 0);
      s[nt] = __builtin_amdgcn_mfma_f32_16x16x32_bf16(kf[nt][1], qf[1], s[nt], 0, 0, 0);
    }
#pragma unroll
    for (int nt = 0; nt < 4; ++nt) {
      float p[4];
#pragma unroll
      for (int r = 0; r < 4; ++r) {
        int j = j0 + nt * 16 + lg * 4 + r;
        p[r] = (j < tq) ? __expf(s[nt][r] - m0) : 0.f;
        lsum += p[r];
      }
      unsigned int w0, w1;
      asm("v_cvt_pk_bf16_f32 %0, %1, %2" : "=v"(w0) : "v"(p[0]), "v"(p[1]));
      asm("v_cvt_pk_bf16_f32 %0, %1, %2" : "=v"(w1) : "v"(p[2]), "v"(p[3]));
      uint2 pk; pk.x = w0; pk.y = w1;
      *(uint2*)(pb + nt * 32 + lg * 8) = pk;
    }
#pragma unroll
    for (int ks = 0; ks < 2; ++ks) {
      short8 pf = *(const short8*)(pb + ks * 64 + lg * 16);
#pragma unroll
      for (int mt = 0; mt < 4; ++mt)
        accO[mt] = __builtin_amdgcn_mfma_f32_16x16x32_bf16(vf[mt][ks], pf, accO[mt], 0, 0, 0);
    }
    asm volatile("s_waitcnt vmcnt(0)" ::: "memory");
    __syncthreads();
  }

  // epilogue: per-q denominator, packed bf16 stores
  {
    float v = lsum;
    v += __shfl_xor(v, 16, 64);
    v += __shfl_xor(v, 32, 64);
    float inv = 1.f / v;
    if (tq < T_) {
      unsigned short* yp = Yh + (size_t)tq * C_;
#pragma unroll
      for (int mt = 0; mt < 4; ++mt) {
        float o0 = accO[mt][0] * inv, o1 = accO[mt][1] * inv;
        float o2 = accO[mt][2] * inv, o3 = accO[mt][3] * inv;
        unsigned int u0, u1;
        asm("v_cvt_pk_bf16_f32 %0, %1, %2" : "=v"(u0) : "v"(o0), "v"(o1));
        asm("v_cvt_pk_bf16_f32 %0, %1, %2" : "=v"(u1) : "v"(o2), "v"(o3));
        uint2 pk; pk.x = u0; pk.y = u1;
        *(uint2*)(yp + mt * 16 + lg * 4) = pk;
      }
    }
  }
#undef STAGE_KV
}

extern "C" void kernel_launch(void* const* d_in, const int* in_sizes, int n_in,
                              void* d_out, int out_size, void* d_ws, size_t ws_size,
                              hipStream_t stream) {
  const float* x          = (const float*)d_in[0];
  const float* W_la       = (const float*)d_in[1];
  const float* la_coef    = (const float*)d_in[2];
  const float* W_v        = (const float*)d_in[3];
  const float* v_coef     = (const float*)d_in[4];
  const float* kernel_bet = (const float*)d_in[5];
  const float* value_bet  = (const float*)d_in[6];
  const float* W_proj     = (const float*)d_in[7];
  float* out = (float*)d_out;

  float* ws = (float*)d_ws;
  const size_t NTOK = (size_t)B_ * T_ * C_;
  const size_t NSEGTOT = (size_t)B_ * NH * NSEG * HS;
  float* uxv     = ws;
  float* segend  = uxv + (size_t)B_ * T_ * CX;
  float* carryin = segend + NSEGTOT;
  __hip_bfloat16* kb16 = (__hip_bfloat16*)(carryin + NSEGTOT);
  __hip_bfloat16* vt16 = kb16 + NTOK;
  __hip_bfloat16* xb   = vt16 + NTOK;
  __hip_bfloat16* Wcat = xb + NTOK;
  __hip_bfloat16* Wpb  = Wcat + (size_t)CX * C_;
  __hip_bfloat16* yb   = xb;  // alias: xb dead after gemm1

  const int M = B_ * T_;

  cast_all<<<2048, 256, 0, stream>>>(x, W_la, W_v, W_proj, xb, Wcat, Wpb);

  gemm_bf16<<<dim3(M / 128, CX / 128), 256, 0, stream>>>(xb, Wcat, uxv, M, CX, C_);

  scan_a<<<dim3(B_ * NH * NSEG / 4), 256, 0, stream>>>(uxv, la_coef, segend);
  scan_b<<<dim3((B_ * NH * HS + 255) / 256), 256, 0, stream>>>(la_coef, segend, carryin);
  scan_c_norm<<<dim3(B_ * NH * NSEG / 4), 256, 0, stream>>>(la_coef, kernel_bet, carryin, uxv, kb16);

  vbuild_t<<<dim3(T_ / 64, B_ * NH), 256, 0, stream>>>(uxv, v_coef, value_bet, vt16);

  attn5<<<dim3(B_ * NH, 32), 256, 0, stream>>>(kb16, vt16, kernel_bet, yb);

  gemm_bf16<<<dim3(M / 128, C_ / 128), 256, 0, stream>>>(yb, Wpb, out, M, C_, C_);
}

// Round 8
// 112.379 us; speedup vs baseline: 19.8639x; 1.0152x over previous
//
#include <hip/hip_runtime.h>
#include <hip/hip_bf16.h>
#include <math.h>

#define B_   2
#define T_   2048
#define C_   768
#define NH   12
#define HS   64
#define NSEG 64
#define SEGLEN 32
#define CX   1536   // uxv row stride (u | xv)

typedef __attribute__((ext_vector_type(8))) short short8;
typedef __attribute__((ext_vector_type(4))) short short4v;
typedef __attribute__((ext_vector_type(4))) float f32x4;

static __device__ inline unsigned short f2b(float f) {
  __hip_bfloat16 h = __float2bfloat16(f);
  unsigned short u;
  __builtin_memcpy(&u, &h, 2);
  return u;
}

#define GLOAD_LDS16(gp, lp)                                                        \
  __builtin_amdgcn_global_load_lds((const __attribute__((address_space(1))) void*)(gp), \
                                   (__attribute__((address_space(3))) void*)(lp), 16, 0, 0)

// ---------------- fused f32 -> bf16 casts (x, W_la|W_v -> Wcat, W_proj) -------------
__global__ __launch_bounds__(256) void cast_all(const float* __restrict__ x,
                                                const float* __restrict__ wla,
                                                const float* __restrict__ wv,
                                                const float* __restrict__ wp,
                                                __hip_bfloat16* __restrict__ xb,
                                                __hip_bfloat16* __restrict__ wcat,
                                                __hip_bfloat16* __restrict__ wpb) {
  const int NX4 = (B_ * T_ * C_) / 4;     // 786432
  const int NW4 = (C_ * C_) / 4;          // 147456
  const int TOT = NX4 + 3 * NW4;
  int i = blockIdx.x * 256 + threadIdx.x;
  int st = gridDim.x * 256;
  for (; i < TOT; i += st) {
    const float* s;
    unsigned short* d;
    if (i < NX4) { s = x + (size_t)i * 4; d = (unsigned short*)xb + (size_t)i * 4; }
    else if (i < NX4 + NW4) { int j = i - NX4; s = wla + (size_t)j * 4; d = (unsigned short*)wcat + (size_t)j * 4; }
    else if (i < NX4 + 2 * NW4) { int j = i - NX4 - NW4; s = wv + (size_t)j * 4; d = (unsigned short*)wcat + (size_t)(C_ * C_) + (size_t)j * 4; }
    else { int j = i - NX4 - 2 * NW4; s = wp + (size_t)j * 4; d = (unsigned short*)wpb + (size_t)j * 4; }
    float4 v = *(const float4*)s;
    short4v o;
    o.x = (short)f2b(v.x); o.y = (short)f2b(v.y); o.z = (short)f2b(v.z); o.w = (short)f2b(v.w);
    *(short4v*)d = o;
  }
}

// ---------------- bf16 MFMA GEMM: C[m,n] = sum_k A[m,k] * Bw[n,k], C f32 -------------
// BM x 128 tile, BK=64, 4 waves. BM=128: waves 2x2 (64x64 each). BM=64: waves 1x4 (64x32).
template <int BM>
__global__ __launch_bounds__(256) void gemm_bf16(const __hip_bfloat16* __restrict__ A,
                                                 const __hip_bfloat16* __restrict__ Bw,
                                                 float* __restrict__ C,
                                                 int M, int N, int K) {
  __shared__ __hip_bfloat16 As[BM * 64];
  __shared__ __hip_bfloat16 Bs[128 * 64];
  const int tid = threadIdx.x;
  const int w = tid >> 6, lane = tid & 63;
  const int bm = blockIdx.x * BM, bn = blockIdx.y * 128;
  const int q16 = lane & 15, lg = lane >> 4;

  constexpr int NACC = (BM == 128) ? 4 : 2;
  f32x4 acc[4][NACC];
#pragma unroll
  for (int i = 0; i < 4; ++i)
#pragma unroll
    for (int j = 0; j < NACC; ++j) acc[i][j] = (f32x4){0.f, 0.f, 0.f, 0.f};

  const int srow = (lane >> 3);
  const int soff0 = (lane & 7) * 16;
  const int sw = (lane & 7) << 4;
  constexpr int ACH = BM / 8;                 // A chunks
  constexpr int CPW = (ACH + 16) / 4;         // chunks per wave

  for (int k0 = 0; k0 < K; k0 += 64) {
    __syncthreads();
#pragma unroll
    for (int c = 0; c < CPW; ++c) {
      int gc = w * CPW + c;
      int isB = gc >= ACH;
      int ci = isB ? gc - ACH : gc;
      int row = ci * 8 + srow;
      int soff = soff0 ^ ((row & 7) << 4);
      const __hip_bfloat16* gp =
          (isB ? Bw + (size_t)(bn + row) * K : A + (size_t)(bm + row) * K) + k0 + (soff >> 1);
      __hip_bfloat16* lp = (isB ? Bs : As) + ci * 512;
      GLOAD_LDS16(gp, lp);
    }
    __syncthreads();
#pragma unroll
    for (int ks = 0; ks < 2; ++ks) {
      short8 af[4], bf[NACC];
      const int colb = ks * 64 + lg * 16;
#pragma unroll
      for (int i = 0; i < 4; ++i) {
        int ra = (BM == 128) ? ((w >> 1) * 64 + i * 16 + q16) : (i * 16 + q16);
        af[i] = *(const short8*)((const char*)As + ra * 128 + (colb ^ sw));
      }
#pragma unroll
      for (int j = 0; j < NACC; ++j) {
        int rb = (BM == 128) ? ((w & 1) * 64 + j * 16 + q16) : (w * 32 + j * 16 + q16);
        bf[j] = *(const short8*)((const char*)Bs + rb * 128 + (colb ^ sw));
      }
#pragma unroll
      for (int i = 0; i < 4; ++i)
#pragma unroll
        for (int j = 0; j < NACC; ++j)
          acc[i][j] = __builtin_amdgcn_mfma_f32_16x16x32_bf16(af[i], bf[j], acc[i][j], 0, 0, 0);
    }
  }
#pragma unroll
  for (int i = 0; i < 4; ++i) {
#pragma unroll
    for (int r = 0; r < 4; ++r) {
      int m = (BM == 128) ? (bm + (w >> 1) * 64 + i * 16 + lg * 4 + r)
                          : (bm + i * 16 + lg * 4 + r);
      int nb = (BM == 128) ? (bn + (w & 1) * 64 + q16) : (bn + w * 32 + q16);
      float* cp = C + (size_t)m * N + nb;
#pragma unroll
      for (int j = 0; j < NACC; ++j) cp[j * 16] = acc[i][j][r];
    }
  }
}

// ---------------- Scan pass A: segment end-carries only (read-only over u) ----------
__global__ __launch_bounds__(256) void scan_seg(const float* __restrict__ uxv,
                                                const float* __restrict__ la_coef,
                                                float* __restrict__ segend) {
  int cid = blockIdx.x * 4 + (threadIdx.x >> 6);  // bh*NSEG + seg
  int d   = threadIdx.x & 63;
  int seg = cid & (NSEG - 1);
  int bh  = cid >> 6;
  int h   = bh % NH;
  int b   = bh / NH;
  float c  = la_coef[h];
  float oc = 1.f - c;
  int t0 = seg * SEGLEN;
  const float* up = uxv + ((size_t)b * T_ + t0) * CX + h * HS + d;
  float y = 0.f;
  for (int i = 0; i < SEGLEN; ++i)
    y = fmaf(c, y, oc * up[(size_t)i * CX]);
  segend[(size_t)cid * HS + d] = y;
}

// ---------------- Scan pass B: sequential combine of segment carries ----------------
__global__ __launch_bounds__(256) void scan_b(const float* __restrict__ la_coef,
                                              const float* __restrict__ segend,
                                              float* __restrict__ carryin) {
  int s = blockIdx.x * 256 + threadIdx.x;  // (b,h,d)
  if (s >= B_ * NH * HS) return;
  int d  = s & 63;
  int bh = s >> 6;
  int h  = bh % NH;
  float c = la_coef[h];
  float cl = c;
#pragma unroll
  for (int i = 0; i < 5; ++i) cl *= cl;  // c^32
  float h0 = 0.f;
  for (int seg = 0; seg < NSEG; ++seg) {
    int cid = bh * NSEG + seg;
    carryin[(size_t)cid * HS + d] = h0;
    h0 = fmaf(cl, h0, segend[(size_t)cid * HS + d]);
  }
}

// ---------------- Scan pass C: recompute scan with carry seed + normalize, bf16 -----
__global__ __launch_bounds__(256) void scan_c_norm(const float* __restrict__ la_coef,
                                                   const float* __restrict__ kernel_beta,
                                                   const float* __restrict__ carryin,
                                                   const float* __restrict__ uxv,
                                                   __hip_bfloat16* __restrict__ kb16) {
  int cid = blockIdx.x * 4 + (threadIdx.x >> 6);
  int d   = threadIdx.x & 63;
  int seg = cid & (NSEG - 1);
  int bh  = cid >> 6;
  int h   = bh % NH;
  int b   = bh / NH;
  float c  = la_coef[h];
  float oc = 1.f - c;
  float bk = __expf(fminf(kernel_beta[h] * 10.f, 5.f));
  int t0 = seg * SEGLEN;
  const float* up = uxv + ((size_t)b * T_ + t0) * CX + h * HS + d;
  __hip_bfloat16* op = kb16 + ((size_t)bh * T_ + t0) * HS + d;
  float y = carryin[(size_t)cid * HS + d];   // true scan value at t0-1
  for (int i = 0; i < SEGLEN; ++i) {
    y = fmaf(c, y, oc * up[(size_t)i * CX]);
    float ss = y * y;
#pragma unroll
    for (int off = 1; off < 64; off <<= 1) ss += __shfl_xor(ss, off, 64);
    float scale = bk / (sqrtf(ss) + 1e-6f);
    op[(size_t)i * HS] = __float2bfloat16(y * scale);
  }
}

// ---------------- v build: shift-mix, normalize, scale; writes TRANSPOSED bf16 ------
__global__ __launch_bounds__(256) void vbuild_t(const float* __restrict__ uxv,
                                                const float* __restrict__ v_coef,
                                                const float* __restrict__ value_beta,
                                                __hip_bfloat16* __restrict__ vt) {
  __shared__ __hip_bfloat16 sm[64][73];
  int t0 = blockIdx.x * 64;
  int bh = blockIdx.y;
  int h = bh % NH, b = bh / NH;
  int w = threadIdx.x >> 6, lane = threadIdx.x & 63;
  float vc = v_coef[h];
  float vb = __expf(fminf(value_beta[h] * 10.f, 5.f));
  for (int i = 0; i < 16; ++i) {
    int tl = w * 16 + i;
    int t = t0 + tl;
    const float* xp = uxv + ((size_t)b * T_ + t) * CX + 768 + h * HS + lane;
    float x0 = *xp;
    float x1 = (t + 1 < T_) ? xp[CX] : 0.f;
    float vf = (1.f - vc) * x1 + vc * x0;
    float ss = vf * vf;
#pragma unroll
    for (int off = 1; off < 64; off <<= 1) ss += __shfl_xor(ss, off, 64);
    sm[tl][lane] = __float2bfloat16(vf * vb / (sqrtf(ss) + 1e-6f));
  }
  __syncthreads();
  int d = threadIdx.x >> 3;
  int c = threadIdx.x & 7;
  for (int i = 0; i < 2; ++i) {
    int dd = d + i * 32;
    short8 v;
#pragma unroll
    for (int k = 0; k < 8; ++k)
      v[k] = (short)((const unsigned short*)&sm[c * 8 + k][dd])[0];
    *(short8*)((unsigned short*)vt + ((size_t)bh * HS + dd) * T_ + t0 + c * 8) = v;
  }
}

// ---------------- attention v6: counted-vmcnt pipeline, raw barriers, setprio -------
// Kg (B,NH,T,HS) bf16; Vtg (B,NH,HS,T) bf16; Y (B,T,C) bf16.
// grid = (24 bh, 32 qtiles): all q-blocks of one bh land on the same XCD (24 % 8 == 0).
__global__ __launch_bounds__(256, 3) void attn6(const __hip_bfloat16* __restrict__ Kg,
                                                const __hip_bfloat16* __restrict__ Vtg,
                                                const float* __restrict__ kernel_beta,
                                                __hip_bfloat16* __restrict__ Y) {
  __shared__ __hip_bfloat16 Kt[2][64 * 64];   // [buf][row*64+col], staged swizzled
  __shared__ __hip_bfloat16 Vt[2][64 * 64];   // rows = d
  __shared__ char Pl[4][2304];                // per-wave P slice: 16 rows x 144B
  const int bh = blockIdx.x;
  const int b = bh / NH, h = bh % NH;
  const int w = threadIdx.x >> 6, lane = threadIdx.x & 63;
  const int q16 = lane & 15, lg = lane >> 4;
  const int it = 31 - blockIdx.y;            // heavy-first
  const int qb0 = 1 + it * 64;
  float bk = __expf(fminf(kernel_beta[h] * 10.f, 5.f));
  float m0 = bk * bk;
  const unsigned short* Kh = (const unsigned short*)Kg + (size_t)bh * T_ * HS;
  const unsigned short* Vh = (const unsigned short*)Vtg + (size_t)bh * HS * T_;
  unsigned short* Yh = (unsigned short*)Y + (size_t)b * T_ * C_ + h * HS;

  if (it == 0 && w == 0) Yh[lane] = 0;  // t=0 row zero

  // this wave's 16 q rows; Q fragment (B-operand): lane holds q-col = q16
  const int tq = qb0 + w * 16 + q16;
  short8 qf[2];
  {
    int tqc = tq > T_ - 1 ? T_ - 1 : tq;
#pragma unroll
    for (int ks = 0; ks < 2; ++ks)
      qf[ks] = *(const short8*)(Kh + (size_t)tqc * HS + ks * 32 + lg * 8);
  }

  f32x4 zero = {0.f, 0.f, 0.f, 0.f};
  f32x4 accO[4];
#pragma unroll
  for (int mt = 0; mt < 4; ++mt) accO[mt] = zero;
  float lsum = 0.f;

  char* pb = &Pl[w][0] + q16 * 144;
  const int swr = (q16 & 7) << 4;  // read-side XOR swizzle (row&7)<<4, row = nt*16+q16

  // staging geometry: per buffer, K tile = 8 chunks of 8 rows x 128B; same for V.
  const int srow = lane >> 3;                       // 0..7
  const int soff = ((lane & 7) << 4) ^ (srow << 4); // inverse-swizzled source byte col

  const int NT = (qb0 + 126) >> 6;  // tiles covering keys j <= qb0+62

#define STAGE_KV(buf, j0)                                                             \
  {                                                                                   \
    _Pragma("unroll")                                                                 \
    for (int n = 0; n < 2; ++n) {                                                     \
      int ch = w * 2 + n;                                                             \
      int row = ch * 8 + srow;                                                        \
      GLOAD_LDS16((const char*)(Kh + (size_t)((j0) + row) * HS) + soff,               \
                  &Kt[buf][ch * 512]);                                                \
      GLOAD_LDS16((const char*)(Vh + (size_t)row * T_ + (j0)) + soff,                 \
                  &Vt[buf][ch * 512]);                                                \
    }                                                                                 \
  }

  STAGE_KV(0, 0);

  for (int kt = 0; kt < NT; ++kt) {
    const int cur = kt & 1;
    const int j0 = kt * 64;
    // issue next-tile stage, then wait only for CURRENT buffer's loads (counted vmcnt)
    if (kt + 1 < NT) {
      STAGE_KV(cur ^ 1, j0 + 64);
      asm volatile("s_waitcnt vmcnt(4)" ::: "memory");
    } else {
      asm volatile("s_waitcnt vmcnt(0)" ::: "memory");
    }
    __builtin_amdgcn_s_barrier();
    __builtin_amdgcn_sched_barrier(0);

    const char* Kb = (const char*)&Kt[cur][0];
    const char* Vb = (const char*)&Vt[cur][0];
    short8 kf[4][2], vf[4][2];
#pragma unroll
    for (int nt = 0; nt < 4; ++nt)
#pragma unroll
      for (int ks = 0; ks < 2; ++ks) {
        const int colb = ks * 64 + lg * 16;
        kf[nt][ks] = *(const short8*)(Kb + (nt * 16 + q16) * 128 + (colb ^ swr));
        vf[nt][ks] = *(const short8*)(Vb + (nt * 16 + q16) * 128 + (colb ^ swr));
      }
    f32x4 s[4];
    __builtin_amdgcn_s_setprio(1);
#pragma unroll
    for (int nt = 0; nt < 4; ++nt) {
      s[nt] = __builtin_amdgcn_mfma_f32_16x16x32_bf16(kf[nt][0], qf[0], zero, 0, 0, 0);
      s[nt] = __builtin_amdgcn_mfma_f32_16x16x32_bf16(kf[nt][1], qf[1], s[nt], 0, 0, 0);
    }
    __builtin_amdgcn_s_setprio(0);
#pragma unroll
    for (int nt = 0; nt < 4; ++nt) {
      float p[4];
#pragma unroll
      for (int r = 0; r < 4; ++r) {
        int j = j0 + nt * 16 + lg * 4 + r;
        p[r] = (j < tq) ? __expf(s[nt][r] - m0) : 0.f;
        lsum += p[r];
      }
      unsigned int w0, w1;
      asm("v_cvt_pk_bf16_f32 %0, %1, %2" : "=v"(w0) : "v"(p[0]), "v"(p[1]));
      asm("v_cvt_pk_bf16_f32 %0, %1, %2" : "=v"(w1) : "v"(p[2]), "v"(p[3]));
      uint2 pk; pk.x = w0; pk.y = w1;
      *(uint2*)(pb + nt * 32 + lg * 8) = pk;
    }
    __builtin_amdgcn_s_setprio(1);
#pragma unroll
    for (int ks = 0; ks < 2; ++ks) {
      short8 pf = *(const short8*)(pb + ks * 64 + lg * 16);
#pragma unroll
      for (int mt = 0; mt < 4; ++mt)
        accO[mt] = __builtin_amdgcn_mfma_f32_16x16x32_bf16(vf[mt][ks], pf, accO[mt], 0, 0, 0);
    }
    __builtin_amdgcn_s_setprio(0);
    // all this wave's LDS reads of buf cur are complete (consumed); sync before overwrite
    asm volatile("s_waitcnt lgkmcnt(0)" ::: "memory");
    __builtin_amdgcn_s_barrier();
  }

  // epilogue: per-q denominator, packed bf16 stores
  {
    float v = lsum;
    v += __shfl_xor(v, 16, 64);
    v += __shfl_xor(v, 32, 64);
    float inv = 1.f / v;
    if (tq < T_) {
      unsigned short* yp = Yh + (size_t)tq * C_;
#pragma unroll
      for (int mt = 0; mt < 4; ++mt) {
        float o0 = accO[mt][0] * inv, o1 = accO[mt][1] * inv;
        float o2 = accO[mt][2] * inv, o3 = accO[mt][3] * inv;
        unsigned int u0, u1;
        asm("v_cvt_pk_bf16_f32 %0, %1, %2" : "=v"(u0) : "v"(o0), "v"(o1));
        asm("v_cvt_pk_bf16_f32 %0, %1, %2" : "=v"(u1) : "v"(o2), "v"(o3));
        uint2 pk; pk.x = u0; pk.y = u1;
        *(uint2*)(yp + mt * 16 + lg * 4) = pk;
      }
    }
  }
#undef STAGE_KV
}

extern "C" void kernel_launch(void* const* d_in, const int* in_sizes, int n_in,
                              void* d_out, int out_size, void* d_ws, size_t ws_size,
                              hipStream_t stream) {
  const float* x          = (const float*)d_in[0];
  const float* W_la       = (const float*)d_in[1];
  const float* la_coef    = (const float*)d_in[2];
  const float* W_v        = (const float*)d_in[3];
  const float* v_coef     = (const float*)d_in[4];
  const float* kernel_bet = (const float*)d_in[5];
  const float* value_bet  = (const float*)d_in[6];
  const float* W_proj     = (const float*)d_in[7];
  float* out = (float*)d_out;

  float* ws = (float*)d_ws;
  const size_t NTOK = (size_t)B_ * T_ * C_;
  const size_t NSEGTOT = (size_t)B_ * NH * NSEG * HS;
  float* uxv     = ws;
  float* segend  = uxv + (size_t)B_ * T_ * CX;
  float* carryin = segend + NSEGTOT;
  __hip_bfloat16* kb16 = (__hip_bfloat16*)(carryin + NSEGTOT);
  __hip_bfloat16* vt16 = kb16 + NTOK;
  __hip_bfloat16* xb   = vt16 + NTOK;
  __hip_bfloat16* Wcat = xb + NTOK;
  __hip_bfloat16* Wpb  = Wcat + (size_t)CX * C_;
  __hip_bfloat16* yb   = xb;  // alias: xb dead after gemm1

  const int M = B_ * T_;

  cast_all<<<2048, 256, 0, stream>>>(x, W_la, W_v, W_proj, xb, Wcat, Wpb);

  gemm_bf16<128><<<dim3(M / 128, CX / 128), 256, 0, stream>>>(xb, Wcat, uxv, M, CX, C_);

  scan_seg<<<dim3(B_ * NH * NSEG / 4), 256, 0, stream>>>(uxv, la_coef, segend);
  scan_b<<<dim3((B_ * NH * HS + 255) / 256), 256, 0, stream>>>(la_coef, segend, carryin);
  scan_c_norm<<<dim3(B_ * NH * NSEG / 4), 256, 0, stream>>>(la_coef, kernel_bet, carryin, uxv, kb16);

  vbuild_t<<<dim3(T_ / 64, B_ * NH), 256, 0, stream>>>(uxv, v_coef, value_bet, vt16);

  attn6<<<dim3(B_ * NH, 32), 256, 0, stream>>>(kb16, vt16, kernel_bet, yb);

  gemm_bf16<64><<<dim3(M / 64, C_ / 128), 256, 0, stream>>>(yb, Wpb, out, M, C_, C_);
}

// Round 9
// 110.699 us; speedup vs baseline: 20.1654x; 1.0152x over previous
//
#include <hip/hip_runtime.h>
#include <hip/hip_bf16.h>
#include <math.h>

#define B_   2
#define T_   2048
#define C_   768
#define NH   12
#define HS   64
#define NSEG 64
#define SEGLEN 32
#define CX   1536   // uxv row stride (u | xv)

typedef __attribute__((ext_vector_type(8))) short short8;
typedef __attribute__((ext_vector_type(4))) short short4v;
typedef __attribute__((ext_vector_type(4))) float f32x4;

static __device__ inline unsigned short f2b(float f) {
  __hip_bfloat16 h = __float2bfloat16(f);
  unsigned short u;
  __builtin_memcpy(&u, &h, 2);
  return u;
}

#define GLOAD_LDS16(gp, lp)                                                        \
  __builtin_amdgcn_global_load_lds((const __attribute__((address_space(1))) void*)(gp), \
                                   (__attribute__((address_space(3))) void*)(lp), 16, 0, 0)

// ---------------- fused f32 -> bf16 casts (x, W_la|W_v -> Wcat, W_proj) -------------
__global__ __launch_bounds__(256) void cast_all(const float* __restrict__ x,
                                                const float* __restrict__ wla,
                                                const float* __restrict__ wv,
                                                const float* __restrict__ wp,
                                                __hip_bfloat16* __restrict__ xb,
                                                __hip_bfloat16* __restrict__ wcat,
                                                __hip_bfloat16* __restrict__ wpb) {
  const int NX4 = (B_ * T_ * C_) / 4;     // 786432
  const int NW4 = (C_ * C_) / 4;          // 147456
  const int TOT = NX4 + 3 * NW4;
  int i = blockIdx.x * 256 + threadIdx.x;
  int st = gridDim.x * 256;
  for (; i < TOT; i += st) {
    const float* s;
    unsigned short* d;
    if (i < NX4) { s = x + (size_t)i * 4; d = (unsigned short*)xb + (size_t)i * 4; }
    else if (i < NX4 + NW4) { int j = i - NX4; s = wla + (size_t)j * 4; d = (unsigned short*)wcat + (size_t)j * 4; }
    else if (i < NX4 + 2 * NW4) { int j = i - NX4 - NW4; s = wv + (size_t)j * 4; d = (unsigned short*)wcat + (size_t)(C_ * C_) + (size_t)j * 4; }
    else { int j = i - NX4 - 2 * NW4; s = wp + (size_t)j * 4; d = (unsigned short*)wpb + (size_t)j * 4; }
    float4 v = *(const float4*)s;
    short4v o;
    o.x = (short)f2b(v.x); o.y = (short)f2b(v.y); o.z = (short)f2b(v.z); o.w = (short)f2b(v.w);
    *(short4v*)d = o;
  }
}

// ---------------- bf16 MFMA GEMM: C[m,n] = sum_k A[m,k] * Bw[n,k], C f32 -------------
// BM x 128 tile, BK=64, 4 waves. BM=64: waves 1x4 (64x32 each).
template <int BM>
__global__ __launch_bounds__(256) void gemm_bf16(const __hip_bfloat16* __restrict__ A,
                                                 const __hip_bfloat16* __restrict__ Bw,
                                                 float* __restrict__ C,
                                                 int M, int N, int K) {
  __shared__ __hip_bfloat16 As[BM * 64];
  __shared__ __hip_bfloat16 Bs[128 * 64];
  const int tid = threadIdx.x;
  const int w = tid >> 6, lane = tid & 63;
  const int bm = blockIdx.x * BM, bn = blockIdx.y * 128;
  const int q16 = lane & 15, lg = lane >> 4;

  constexpr int NACC = (BM == 128) ? 4 : 2;
  f32x4 acc[4][NACC];
#pragma unroll
  for (int i = 0; i < 4; ++i)
#pragma unroll
    for (int j = 0; j < NACC; ++j) acc[i][j] = (f32x4){0.f, 0.f, 0.f, 0.f};

  const int srow = (lane >> 3);
  const int soff0 = (lane & 7) * 16;
  const int sw = (lane & 7) << 4;
  constexpr int ACH = BM / 8;                 // A chunks
  constexpr int CPW = (ACH + 16) / 4;         // chunks per wave

  for (int k0 = 0; k0 < K; k0 += 64) {
    __syncthreads();
#pragma unroll
    for (int c = 0; c < CPW; ++c) {
      int gc = w * CPW + c;
      int isB = gc >= ACH;
      int ci = isB ? gc - ACH : gc;
      int row = ci * 8 + srow;
      int soff = soff0 ^ ((row & 7) << 4);
      const __hip_bfloat16* gp =
          (isB ? Bw + (size_t)(bn + row) * K : A + (size_t)(bm + row) * K) + k0 + (soff >> 1);
      __hip_bfloat16* lp = (isB ? Bs : As) + ci * 512;
      GLOAD_LDS16(gp, lp);
    }
    __syncthreads();
#pragma unroll
    for (int ks = 0; ks < 2; ++ks) {
      short8 af[4], bf[NACC];
      const int colb = ks * 64 + lg * 16;
#pragma unroll
      for (int i = 0; i < 4; ++i) {
        int ra = (BM == 128) ? ((w >> 1) * 64 + i * 16 + q16) : (i * 16 + q16);
        af[i] = *(const short8*)((const char*)As + ra * 128 + (colb ^ sw));
      }
#pragma unroll
      for (int j = 0; j < NACC; ++j) {
        int rb = (BM == 128) ? ((w & 1) * 64 + j * 16 + q16) : (w * 32 + j * 16 + q16);
        bf[j] = *(const short8*)((const char*)Bs + rb * 128 + (colb ^ sw));
      }
#pragma unroll
      for (int i = 0; i < 4; ++i)
#pragma unroll
        for (int j = 0; j < NACC; ++j)
          acc[i][j] = __builtin_amdgcn_mfma_f32_16x16x32_bf16(af[i], bf[j], acc[i][j], 0, 0, 0);
    }
  }
#pragma unroll
  for (int i = 0; i < 4; ++i) {
#pragma unroll
    for (int r = 0; r < 4; ++r) {
      int m = (BM == 128) ? (bm + (w >> 1) * 64 + i * 16 + lg * 4 + r)
                          : (bm + i * 16 + lg * 4 + r);
      int nb = (BM == 128) ? (bn + (w & 1) * 64 + q16) : (bn + w * 32 + q16);
      float* cp = C + (size_t)m * N + nb;
#pragma unroll
      for (int j = 0; j < NACC; ++j) cp[j * 16] = acc[i][j][r];
    }
  }
}

// ---------------- Scan pass A: segment end-carries only (read-only over u) ----------
__global__ __launch_bounds__(256) void scan_seg(const float* __restrict__ uxv,
                                                const float* __restrict__ la_coef,
                                                float* __restrict__ segend) {
  int cid = blockIdx.x * 4 + (threadIdx.x >> 6);  // bh*NSEG + seg
  int d   = threadIdx.x & 63;
  int seg = cid & (NSEG - 1);
  int bh  = cid >> 6;
  int h   = bh % NH;
  int b   = bh / NH;
  float c  = la_coef[h];
  float oc = 1.f - c;
  int t0 = seg * SEGLEN;
  const float* up = uxv + ((size_t)b * T_ + t0) * CX + h * HS + d;
  float y = 0.f;
  for (int i = 0; i < SEGLEN; ++i)
    y = fmaf(c, y, oc * up[(size_t)i * CX]);
  segend[(size_t)cid * HS + d] = y;
}

// ---------------- Scan pass B: sequential combine of segment carries ----------------
__global__ __launch_bounds__(256) void scan_b(const float* __restrict__ la_coef,
                                              const float* __restrict__ segend,
                                              float* __restrict__ carryin) {
  int s = blockIdx.x * 256 + threadIdx.x;  // (b,h,d)
  if (s >= B_ * NH * HS) return;
  int d  = s & 63;
  int bh = s >> 6;
  int h  = bh % NH;
  float c = la_coef[h];
  float cl = c;
#pragma unroll
  for (int i = 0; i < 5; ++i) cl *= cl;  // c^32
  float h0 = 0.f;
  for (int seg = 0; seg < NSEG; ++seg) {
    int cid = bh * NSEG + seg;
    carryin[(size_t)cid * HS + d] = h0;
    h0 = fmaf(cl, h0, segend[(size_t)cid * HS + d]);
  }
}

// ---------------- Scan pass C: recompute scan with carry seed + normalize, bf16 -----
__global__ __launch_bounds__(256) void scan_c_norm(const float* __restrict__ la_coef,
                                                   const float* __restrict__ kernel_beta,
                                                   const float* __restrict__ carryin,
                                                   const float* __restrict__ uxv,
                                                   __hip_bfloat16* __restrict__ kb16) {
  int cid = blockIdx.x * 4 + (threadIdx.x >> 6);
  int d   = threadIdx.x & 63;
  int seg = cid & (NSEG - 1);
  int bh  = cid >> 6;
  int h   = bh % NH;
  int b   = bh / NH;
  float c  = la_coef[h];
  float oc = 1.f - c;
  float bk = __expf(fminf(kernel_beta[h] * 10.f, 5.f));
  int t0 = seg * SEGLEN;
  const float* up = uxv + ((size_t)b * T_ + t0) * CX + h * HS + d;
  __hip_bfloat16* op = kb16 + ((size_t)bh * T_ + t0) * HS + d;
  float y = carryin[(size_t)cid * HS + d];   // true scan value at t0-1
  for (int i = 0; i < SEGLEN; ++i) {
    y = fmaf(c, y, oc * up[(size_t)i * CX]);
    float ss = y * y;
#pragma unroll
    for (int off = 1; off < 64; off <<= 1) ss += __shfl_xor(ss, off, 64);
    float scale = bk / (sqrtf(ss) + 1e-6f);
    op[(size_t)i * HS] = __float2bfloat16(y * scale);
  }
}

// ---------------- v build: shift-mix, normalize, scale; writes TRANSPOSED bf16 ------
__global__ __launch_bounds__(256) void vbuild_t(const float* __restrict__ uxv,
                                                const float* __restrict__ v_coef,
                                                const float* __restrict__ value_beta,
                                                __hip_bfloat16* __restrict__ vt) {
  __shared__ __hip_bfloat16 sm[64][73];
  int t0 = blockIdx.x * 64;
  int bh = blockIdx.y;
  int h = bh % NH, b = bh / NH;
  int w = threadIdx.x >> 6, lane = threadIdx.x & 63;
  float vc = v_coef[h];
  float vb = __expf(fminf(value_beta[h] * 10.f, 5.f));
  for (int i = 0; i < 16; ++i) {
    int tl = w * 16 + i;
    int t = t0 + tl;
    const float* xp = uxv + ((size_t)b * T_ + t) * CX + 768 + h * HS + lane;
    float x0 = *xp;
    float x1 = (t + 1 < T_) ? xp[CX] : 0.f;
    float vf = (1.f - vc) * x1 + vc * x0;
    float ss = vf * vf;
#pragma unroll
    for (int off = 1; off < 64; off <<= 1) ss += __shfl_xor(ss, off, 64);
    sm[tl][lane] = __float2bfloat16(vf * vb / (sqrtf(ss) + 1e-6f));
  }
  __syncthreads();
  int d = threadIdx.x >> 3;
  int c = threadIdx.x & 7;
  for (int i = 0; i < 2; ++i) {
    int dd = d + i * 32;
    short8 v;
#pragma unroll
    for (int k = 0; k < 8; ++k)
      v[k] = (short)((const unsigned short*)&sm[c * 8 + k][dd])[0];
    *(short8*)((unsigned short*)vt + ((size_t)bh * HS + dd) * T_ + t0 + c * 8) = v;
  }
}

// ---------------- attention v7: cross-tile software pipeline (QK(kt) || SM+PV(kt-1)) -
// Kg (B,NH,T,HS) bf16; Vtg (B,NH,HS,T) bf16; Y (B,T,C) bf16.
// K double-buffered, V TRIPLE-buffered (PV(kt-1) reads V[kt-1] while V[kt+1] stages).
// grid = (24 bh, 32 qtiles): all q-blocks of one bh land on the same XCD (24 % 8 == 0).
__global__ __launch_bounds__(256, 4) void attn7(const __hip_bfloat16* __restrict__ Kg,
                                                const __hip_bfloat16* __restrict__ Vtg,
                                                const float* __restrict__ kernel_beta,
                                                __hip_bfloat16* __restrict__ Y) {
  __shared__ __hip_bfloat16 Kt[2][64 * 64];   // staged swizzled, rows = key j
  __shared__ __hip_bfloat16 Vt[3][64 * 64];   // staged swizzled, rows = d
  __shared__ char Pl[4][2304];                // per-wave P slice: 16 rows x 144B
  const int bh = blockIdx.x;
  const int b = bh / NH, h = bh % NH;
  const int w = threadIdx.x >> 6, lane = threadIdx.x & 63;
  const int q16 = lane & 15, lg = lane >> 4;
  const int it = 31 - blockIdx.y;            // heavy-first
  const int qb0 = 1 + it * 64;
  float bk = __expf(fminf(kernel_beta[h] * 10.f, 5.f));
  float m0 = bk * bk;
  const unsigned short* Kh = (const unsigned short*)Kg + (size_t)bh * T_ * HS;
  const unsigned short* Vh = (const unsigned short*)Vtg + (size_t)bh * HS * T_;
  unsigned short* Yh = (unsigned short*)Y + (size_t)b * T_ * C_ + h * HS;

  if (it == 0 && w == 0) Yh[lane] = 0;  // t=0 row zero

  // this wave's 16 q rows; Q fragment (B-operand): lane holds q-col = q16
  const int tq = qb0 + w * 16 + q16;
  short8 qf[2];
  {
    int tqc = tq > T_ - 1 ? T_ - 1 : tq;
#pragma unroll
    for (int ks = 0; ks < 2; ++ks)
      qf[ks] = *(const short8*)(Kh + (size_t)tqc * HS + ks * 32 + lg * 8);
  }

  f32x4 zero = {0.f, 0.f, 0.f, 0.f};
  f32x4 accO[4];
#pragma unroll
  for (int mt = 0; mt < 4; ++mt) accO[mt] = zero;
  float lsum = 0.f;
  f32x4 sp[4];  // S of previous tile (pipeline register)

  char* pb = &Pl[w][0] + q16 * 144;
  const int swr = (q16 & 7) << 4;  // read-side XOR swizzle (row&7)<<4, row = nt*16+q16

  // staging geometry: per buffer, tile = 8 chunks of 8 rows x 128B.
  const int srow = lane >> 3;                       // 0..7
  const int soff = ((lane & 7) << 4) ^ (srow << 4); // inverse-swizzled source byte col

  const int NT = (qb0 + 126) >> 6;  // tiles covering keys j <= qb0+62

#define STAGE_KV(kbuf, vbuf, j0)                                                      \
  {                                                                                   \
    _Pragma("unroll")                                                                 \
    for (int n = 0; n < 2; ++n) {                                                     \
      int ch = w * 2 + n;                                                             \
      int row = ch * 8 + srow;                                                        \
      GLOAD_LDS16((const char*)(Kh + (size_t)((j0) + row) * HS) + soff,               \
                  &Kt[kbuf][ch * 512]);                                               \
      GLOAD_LDS16((const char*)(Vh + (size_t)row * T_ + (j0)) + soff,                 \
                  &Vt[vbuf][ch * 512]);                                               \
    }                                                                                 \
  }

  // softmax + PV for tile tp (S in sp[], V from Vt[tp%3])
#define SM_PV(tp)                                                                     \
  {                                                                                   \
    const int j0p = (tp)*64;                                                          \
    const char* Vb = (const char*)&Vt[(tp) % 3][0];                                   \
    _Pragma("unroll")                                                                 \
    for (int nt = 0; nt < 4; ++nt) {                                                  \
      float p[4];                                                                     \
      _Pragma("unroll")                                                               \
      for (int r = 0; r < 4; ++r) {                                                   \
        int j = j0p + nt * 16 + lg * 4 + r;                                           \
        p[r] = (j < tq) ? __expf(sp[nt][r] - m0) : 0.f;                               \
        lsum += p[r];                                                                 \
      }                                                                               \
      unsigned int w0, w1;                                                            \
      asm("v_cvt_pk_bf16_f32 %0, %1, %2" : "=v"(w0) : "v"(p[0]), "v"(p[1]));          \
      asm("v_cvt_pk_bf16_f32 %0, %1, %2" : "=v"(w1) : "v"(p[2]), "v"(p[3]));          \
      uint2 pk; pk.x = w0; pk.y = w1;                                                 \
      *(uint2*)(pb + nt * 32 + lg * 8) = pk;                                          \
    }                                                                                 \
    __builtin_amdgcn_s_setprio(1);                                                    \
    _Pragma("unroll")                                                                 \
    for (int ks = 0; ks < 2; ++ks) {                                                  \
      short8 pf = *(const short8*)(pb + ks * 64 + lg * 16);                           \
      _Pragma("unroll")                                                               \
      for (int mt = 0; mt < 4; ++mt) {                                                \
        short8 vf = *(const short8*)(Vb + (mt * 16 + q16) * 128 +                     \
                                     ((ks * 64 + lg * 16) ^ swr));                    \
        accO[mt] = __builtin_amdgcn_mfma_f32_16x16x32_bf16(vf, pf, accO[mt], 0, 0, 0);\
      }                                                                               \
    }                                                                                 \
    __builtin_amdgcn_s_setprio(0);                                                    \
  }

  STAGE_KV(0, 0, 0);

  for (int kt = 0; kt < NT; ++kt) {
    const int j0 = kt * 64;
    // stage tile kt+1 (K->Kt[(kt+1)&1], V->Vt[(kt+1)%3]); counted wait for tile kt
    if (kt + 1 < NT) {
      STAGE_KV((kt + 1) & 1, (kt + 1) % 3, j0 + 64);
      asm volatile("s_waitcnt vmcnt(4)" ::: "memory");
    } else {
      asm volatile("s_waitcnt vmcnt(0)" ::: "memory");
    }
    __builtin_amdgcn_s_barrier();
    __builtin_amdgcn_sched_barrier(0);

    // QK for tile kt (chain A)
    const char* Kb = (const char*)&Kt[kt & 1][0];
    short8 kf[4][2];
#pragma unroll
    for (int nt = 0; nt < 4; ++nt)
#pragma unroll
      for (int ks = 0; ks < 2; ++ks)
        kf[nt][ks] = *(const short8*)(Kb + (nt * 16 + q16) * 128 + ((ks * 64 + lg * 16) ^ swr));
    f32x4 sc[4];
    __builtin_amdgcn_s_setprio(1);
#pragma unroll
    for (int nt = 0; nt < 4; ++nt) {
      sc[nt] = __builtin_amdgcn_mfma_f32_16x16x32_bf16(kf[nt][0], qf[0], zero, 0, 0, 0);
      sc[nt] = __builtin_amdgcn_mfma_f32_16x16x32_bf16(kf[nt][1], qf[1], sc[nt], 0, 0, 0);
    }
    __builtin_amdgcn_s_setprio(0);

    // softmax + PV for tile kt-1 (chain B, independent of chain A)
    if (kt > 0) SM_PV(kt - 1);

#pragma unroll
    for (int nt = 0; nt < 4; ++nt) sp[nt] = sc[nt];

    // all LDS reads of this iteration done before buffers are re-staged next iter
    asm volatile("s_waitcnt lgkmcnt(0)" ::: "memory");
    __builtin_amdgcn_s_barrier();
  }
  // drain: softmax + PV for the last tile
  SM_PV(NT - 1);

  // epilogue: per-q denominator, packed bf16 stores
  {
    float v = lsum;
    v += __shfl_xor(v, 16, 64);
    v += __shfl_xor(v, 32, 64);
    float inv = 1.f / v;
    if (tq < T_) {
      unsigned short* yp = Yh + (size_t)tq * C_;
#pragma unroll
      for (int mt = 0; mt < 4; ++mt) {
        float o0 = accO[mt][0] * inv, o1 = accO[mt][1] * inv;
        float o2 = accO[mt][2] * inv, o3 = accO[mt][3] * inv;
        unsigned int u0, u1;
        asm("v_cvt_pk_bf16_f32 %0, %1, %2" : "=v"(u0) : "v"(o0), "v"(o1));
        asm("v_cvt_pk_bf16_f32 %0, %1, %2" : "=v"(u1) : "v"(o2), "v"(o3));
        uint2 pk; pk.x = u0; pk.y = u1;
        *(uint2*)(yp + mt * 16 + lg * 4) = pk;
      }
    }
  }
#undef STAGE_KV
#undef SM_PV
}

extern "C" void kernel_launch(void* const* d_in, const int* in_sizes, int n_in,
                              void* d_out, int out_size, void* d_ws, size_t ws_size,
                              hipStream_t stream) {
  const float* x          = (const float*)d_in[0];
  const float* W_la       = (const float*)d_in[1];
  const float* la_coef    = (const float*)d_in[2];
  const float* W_v        = (const float*)d_in[3];
  const float* v_coef     = (const float*)d_in[4];
  const float* kernel_bet = (const float*)d_in[5];
  const float* value_bet  = (const float*)d_in[6];
  const float* W_proj     = (const float*)d_in[7];
  float* out = (float*)d_out;

  float* ws = (float*)d_ws;
  const size_t NTOK = (size_t)B_ * T_ * C_;
  const size_t NSEGTOT = (size_t)B_ * NH * NSEG * HS;
  float* uxv     = ws;
  float* segend  = uxv + (size_t)B_ * T_ * CX;
  float* carryin = segend + NSEGTOT;
  __hip_bfloat16* kb16 = (__hip_bfloat16*)(carryin + NSEGTOT);
  __hip_bfloat16* vt16 = kb16 + NTOK;
  __hip_bfloat16* xb   = vt16 + NTOK;
  __hip_bfloat16* Wcat = xb + NTOK;
  __hip_bfloat16* Wpb  = Wcat + (size_t)CX * C_;
  __hip_bfloat16* yb   = xb;  // alias: xb dead after gemm1

  const int M = B_ * T_;

  cast_all<<<2048, 256, 0, stream>>>(x, W_la, W_v, W_proj, xb, Wcat, Wpb);

  gemm_bf16<64><<<dim3(M / 64, CX / 128), 256, 0, stream>>>(xb, Wcat, uxv, M, CX, C_);

  scan_seg<<<dim3(B_ * NH * NSEG / 4), 256, 0, stream>>>(uxv, la_coef, segend);
  scan_b<<<dim3((B_ * NH * HS + 255) / 256), 256, 0, stream>>>(la_coef, segend, carryin);
  scan_c_norm<<<dim3(B_ * NH * NSEG / 4), 256, 0, stream>>>(la_coef, kernel_bet, carryin, uxv, kb16);

  vbuild_t<<<dim3(T_ / 64, B_ * NH), 256, 0, stream>>>(uxv, v_coef, value_bet, vt16);

  attn7<<<dim3(B_ * NH, 32), 256, 0, stream>>>(kb16, vt16, kernel_bet, yb);

  gemm_bf16<64><<<dim3(M / 64, C_ / 128), 256, 0, stream>>>(yb, Wpb, out, M, C_, C_);
}

// Round 10
// 104.360 us; speedup vs baseline: 21.3905x; 1.0608x over previous
//
#include <hip/hip_runtime.h>
#include <hip/hip_bf16.h>
#include <math.h>

#define B_   2
#define T_   2048
#define C_   768
#define NH   12
#define HS   64
#define NSEG 64
#define SEGLEN 32
#define CX   1536   // uxv row stride (u | xv)

typedef __attribute__((ext_vector_type(8))) short short8;
typedef __attribute__((ext_vector_type(4))) short short4v;
typedef __attribute__((ext_vector_type(4))) float f32x4;

static __device__ inline unsigned short f2b(float f) {
  __hip_bfloat16 h = __float2bfloat16(f);
  unsigned short u;
  __builtin_memcpy(&u, &h, 2);
  return u;
}
static __device__ inline float b2f(unsigned short u) {
  unsigned int x = ((unsigned int)u) << 16;
  float f;
  __builtin_memcpy(&f, &x, 4);
  return f;
}

#define GLOAD_LDS16(gp, lp)                                                        \
  __builtin_amdgcn_global_load_lds((const __attribute__((address_space(1))) void*)(gp), \
                                   (__attribute__((address_space(3))) void*)(lp), 16, 0, 0)

// ---------------- fused f32 -> bf16 casts (x, W_la|W_v -> Wcat, W_proj) -------------
__global__ __launch_bounds__(256) void cast_all(const float* __restrict__ x,
                                                const float* __restrict__ wla,
                                                const float* __restrict__ wv,
                                                const float* __restrict__ wp,
                                                __hip_bfloat16* __restrict__ xb,
                                                __hip_bfloat16* __restrict__ wcat,
                                                __hip_bfloat16* __restrict__ wpb) {
  const int NX4 = (B_ * T_ * C_) / 4;     // 786432
  const int NW4 = (C_ * C_) / 4;          // 147456
  const int TOT = NX4 + 3 * NW4;
  int i = blockIdx.x * 256 + threadIdx.x;
  int st = gridDim.x * 256;
  for (; i < TOT; i += st) {
    const float* s;
    unsigned short* d;
    if (i < NX4) { s = x + (size_t)i * 4; d = (unsigned short*)xb + (size_t)i * 4; }
    else if (i < NX4 + NW4) { int j = i - NX4; s = wla + (size_t)j * 4; d = (unsigned short*)wcat + (size_t)j * 4; }
    else if (i < NX4 + 2 * NW4) { int j = i - NX4 - NW4; s = wv + (size_t)j * 4; d = (unsigned short*)wcat + (size_t)(C_ * C_) + (size_t)j * 4; }
    else { int j = i - NX4 - 2 * NW4; s = wp + (size_t)j * 4; d = (unsigned short*)wpb + (size_t)j * 4; }
    float4 v = *(const float4*)s;
    short4v o;
    o.x = (short)f2b(v.x); o.y = (short)f2b(v.y); o.z = (short)f2b(v.z); o.w = (short)f2b(v.w);
    *(short4v*)d = o;
  }
}

// ---------------- bf16 MFMA GEMM: C[m,n] = sum_k A[m,k] * Bw[n,k] -------------------
// BM x 128 tile, BK=64, 4 waves. BM=64: waves 1x4 (64x32 each). OB16: bf16 output.
template <int BM, bool OB16>
__global__ __launch_bounds__(256) void gemm_bf16(const __hip_bfloat16* __restrict__ A,
                                                 const __hip_bfloat16* __restrict__ Bw,
                                                 void* __restrict__ Cv,
                                                 int M, int N, int K) {
  __shared__ __hip_bfloat16 As[BM * 64];
  __shared__ __hip_bfloat16 Bs[128 * 64];
  const int tid = threadIdx.x;
  const int w = tid >> 6, lane = tid & 63;
  const int bm = blockIdx.x * BM, bn = blockIdx.y * 128;
  const int q16 = lane & 15, lg = lane >> 4;

  constexpr int NACC = (BM == 128) ? 4 : 2;
  f32x4 acc[4][NACC];
#pragma unroll
  for (int i = 0; i < 4; ++i)
#pragma unroll
    for (int j = 0; j < NACC; ++j) acc[i][j] = (f32x4){0.f, 0.f, 0.f, 0.f};

  const int srow = (lane >> 3);
  const int soff0 = (lane & 7) * 16;
  const int sw = (lane & 7) << 4;
  constexpr int ACH = BM / 8;                 // A chunks
  constexpr int CPW = (ACH + 16) / 4;         // chunks per wave

  for (int k0 = 0; k0 < K; k0 += 64) {
    __syncthreads();
#pragma unroll
    for (int c = 0; c < CPW; ++c) {
      int gc = w * CPW + c;
      int isB = gc >= ACH;
      int ci = isB ? gc - ACH : gc;
      int row = ci * 8 + srow;
      int soff = soff0 ^ ((row & 7) << 4);
      const __hip_bfloat16* gp =
          (isB ? Bw + (size_t)(bn + row) * K : A + (size_t)(bm + row) * K) + k0 + (soff >> 1);
      __hip_bfloat16* lp = (isB ? Bs : As) + ci * 512;
      GLOAD_LDS16(gp, lp);
    }
    __syncthreads();
#pragma unroll
    for (int ks = 0; ks < 2; ++ks) {
      short8 af[4], bf[NACC];
      const int colb = ks * 64 + lg * 16;
#pragma unroll
      for (int i = 0; i < 4; ++i) {
        int ra = (BM == 128) ? ((w >> 1) * 64 + i * 16 + q16) : (i * 16 + q16);
        af[i] = *(const short8*)((const char*)As + ra * 128 + (colb ^ sw));
      }
#pragma unroll
      for (int j = 0; j < NACC; ++j) {
        int rb = (BM == 128) ? ((w & 1) * 64 + j * 16 + q16) : (w * 32 + j * 16 + q16);
        bf[j] = *(const short8*)((const char*)Bs + rb * 128 + (colb ^ sw));
      }
#pragma unroll
      for (int i = 0; i < 4; ++i)
#pragma unroll
        for (int j = 0; j < NACC; ++j)
          acc[i][j] = __builtin_amdgcn_mfma_f32_16x16x32_bf16(af[i], bf[j], acc[i][j], 0, 0, 0);
    }
  }
#pragma unroll
  for (int i = 0; i < 4; ++i) {
#pragma unroll
    for (int r = 0; r < 4; ++r) {
      int m = (BM == 128) ? (bm + (w >> 1) * 64 + i * 16 + lg * 4 + r)
                          : (bm + i * 16 + lg * 4 + r);
      int nb = (BM == 128) ? (bn + (w & 1) * 64 + q16) : (bn + w * 32 + q16);
      if (OB16) {
        unsigned short* cp = (unsigned short*)Cv + (size_t)m * N + nb;
#pragma unroll
        for (int j = 0; j < NACC; ++j) cp[j * 16] = f2b(acc[i][j][r]);
      } else {
        float* cp = (float*)Cv + (size_t)m * N + nb;
#pragma unroll
        for (int j = 0; j < NACC; ++j) cp[j * 16] = acc[i][j][r];
      }
    }
  }
}

// ---------------- Scan pass A: segment end-carries (bf16 u, prefetched loads) -------
__global__ __launch_bounds__(256) void scan_seg(const unsigned short* __restrict__ uxv,
                                                const float* __restrict__ la_coef,
                                                float* __restrict__ segend) {
  int cid = blockIdx.x * 4 + (threadIdx.x >> 6);  // bh*NSEG + seg
  int d   = threadIdx.x & 63;
  int seg = cid & (NSEG - 1);
  int bh  = cid >> 6;
  int h   = bh % NH;
  int b   = bh / NH;
  float c  = la_coef[h];
  float oc = 1.f - c;
  int t0 = seg * SEGLEN;
  const unsigned short* up = uxv + ((size_t)b * T_ + t0) * CX + h * HS + d;
  float uv[SEGLEN];
#pragma unroll
  for (int i = 0; i < SEGLEN; ++i) uv[i] = b2f(up[(size_t)i * CX]);
  float y = 0.f;
#pragma unroll
  for (int i = 0; i < SEGLEN; ++i) y = fmaf(c, y, oc * uv[i]);
  segend[(size_t)cid * HS + d] = y;
}

// ---------------- Scan pass B: sequential combine of segment carries ----------------
__global__ __launch_bounds__(256) void scan_b(const float* __restrict__ la_coef,
                                              const float* __restrict__ segend,
                                              float* __restrict__ carryin) {
  int s = blockIdx.x * 256 + threadIdx.x;  // (b,h,d)
  if (s >= B_ * NH * HS) return;
  int d  = s & 63;
  int bh = s >> 6;
  int h  = bh % NH;
  float c = la_coef[h];
  float cl = c;
#pragma unroll
  for (int i = 0; i < 5; ++i) cl *= cl;  // c^32
  float h0 = 0.f;
  for (int seg = 0; seg < NSEG; ++seg) {
    int cid = bh * NSEG + seg;
    carryin[(size_t)cid * HS + d] = h0;
    h0 = fmaf(cl, h0, segend[(size_t)cid * HS + d]);
  }
}

// ---------------- Fused: scan_c+normalize (blocks 0..383) | vbuild_t (384..1151) ----
__global__ __launch_bounds__(256) void scanc_vbuild(const float* __restrict__ la_coef,
                                                    const float* __restrict__ kernel_beta,
                                                    const float* __restrict__ carryin,
                                                    const unsigned short* __restrict__ uxv,
                                                    const float* __restrict__ v_coef,
                                                    const float* __restrict__ value_beta,
                                                    __hip_bfloat16* __restrict__ kb16,
                                                    __hip_bfloat16* __restrict__ vt) {
  __shared__ __hip_bfloat16 sm[64][73];
  const int NBC = B_ * NH * NSEG / 4;   // 384 scan_c blocks
  if ((int)blockIdx.x < NBC) {
    // ---- scan_c + k-normalize ----
    int cid = blockIdx.x * 4 + (threadIdx.x >> 6);
    int d   = threadIdx.x & 63;
    int seg = cid & (NSEG - 1);
    int bh  = cid >> 6;
    int h   = bh % NH;
    int b   = bh / NH;
    float c  = la_coef[h];
    float oc = 1.f - c;
    float bk = __expf(fminf(kernel_beta[h] * 10.f, 5.f));
    int t0 = seg * SEGLEN;
    const unsigned short* up = uxv + ((size_t)b * T_ + t0) * CX + h * HS + d;
    __hip_bfloat16* op = kb16 + ((size_t)bh * T_ + t0) * HS + d;
    float uv[SEGLEN];
#pragma unroll
    for (int i = 0; i < SEGLEN; ++i) uv[i] = b2f(up[(size_t)i * CX]);
    float y = carryin[(size_t)cid * HS + d];   // true scan value at t0-1
    for (int i = 0; i < SEGLEN; ++i) {
      y = fmaf(c, y, oc * uv[i]);
      float ss = y * y;
#pragma unroll
      for (int off = 1; off < 64; off <<= 1) ss += __shfl_xor(ss, off, 64);
      float scale = bk / (sqrtf(ss) + 1e-6f);
      op[(size_t)i * HS] = __float2bfloat16(y * scale);
    }
  } else {
    // ---- vbuild: shift-mix, normalize, scale; TRANSPOSED bf16 out ----
    int idx = blockIdx.x - NBC;
    int t0 = (idx & 31) * 64;
    int bh = idx >> 5;
    int h = bh % NH, b = bh / NH;
    int w = threadIdx.x >> 6, lane = threadIdx.x & 63;
    float vc = v_coef[h];
    float vb = __expf(fminf(value_beta[h] * 10.f, 5.f));
    for (int i = 0; i < 16; ++i) {
      int tl = w * 16 + i;
      int t = t0 + tl;
      const unsigned short* xp = uxv + ((size_t)b * T_ + t) * CX + 768 + h * HS + lane;
      float x0 = b2f(*xp);
      float x1 = (t + 1 < T_) ? b2f(xp[CX]) : 0.f;
      float vf = (1.f - vc) * x1 + vc * x0;
      float ss = vf * vf;
#pragma unroll
      for (int off = 1; off < 64; off <<= 1) ss += __shfl_xor(ss, off, 64);
      sm[tl][lane] = __float2bfloat16(vf * vb / (sqrtf(ss) + 1e-6f));
    }
    __syncthreads();
    int d = threadIdx.x >> 3;
    int c = threadIdx.x & 7;
    for (int i = 0; i < 2; ++i) {
      int dd = d + i * 32;
      short8 v;
#pragma unroll
      for (int k = 0; k < 8; ++k)
        v[k] = (short)((const unsigned short*)&sm[c * 8 + k][dd])[0];
      *(short8*)((unsigned short*)vt + ((size_t)bh * HS + dd) * T_ + t0 + c * 8) = v;
    }
  }
}

// ---------------- attention v7: cross-tile software pipeline (QK(kt) || SM+PV(kt-1)) -
__global__ __launch_bounds__(256, 4) void attn7(const __hip_bfloat16* __restrict__ Kg,
                                                const __hip_bfloat16* __restrict__ Vtg,
                                                const float* __restrict__ kernel_beta,
                                                __hip_bfloat16* __restrict__ Y) {
  __shared__ __hip_bfloat16 Kt[2][64 * 64];   // staged swizzled, rows = key j
  __shared__ __hip_bfloat16 Vt[3][64 * 64];   // staged swizzled, rows = d
  __shared__ char Pl[4][2304];                // per-wave P slice: 16 rows x 144B
  const int bh = blockIdx.x;
  const int b = bh / NH, h = bh % NH;
  const int w = threadIdx.x >> 6, lane = threadIdx.x & 63;
  const int q16 = lane & 15, lg = lane >> 4;
  const int it = 31 - blockIdx.y;            // heavy-first
  const int qb0 = 1 + it * 64;
  float bk = __expf(fminf(kernel_beta[h] * 10.f, 5.f));
  const float L2E = 1.4426950408889634f;
  float m0l = bk * bk * L2E;                 // fixed shift in log2 domain
  const unsigned short* Kh = (const unsigned short*)Kg + (size_t)bh * T_ * HS;
  const unsigned short* Vh = (const unsigned short*)Vtg + (size_t)bh * HS * T_;
  unsigned short* Yh = (unsigned short*)Y + (size_t)b * T_ * C_ + h * HS;

  if (it == 0 && w == 0) Yh[lane] = 0;  // t=0 row zero

  const int tq = qb0 + w * 16 + q16;
  short8 qf[2];
  {
    int tqc = tq > T_ - 1 ? T_ - 1 : tq;
#pragma unroll
    for (int ks = 0; ks < 2; ++ks)
      qf[ks] = *(const short8*)(Kh + (size_t)tqc * HS + ks * 32 + lg * 8);
  }

  f32x4 zero = {0.f, 0.f, 0.f, 0.f};
  f32x4 accO[4];
#pragma unroll
  for (int mt = 0; mt < 4; ++mt) accO[mt] = zero;
  float lsum = 0.f;
  f32x4 sp[4];  // S of previous tile (pipeline register)

  char* pb = &Pl[w][0] + q16 * 144;
  const int swr = (q16 & 7) << 4;

  const int srow = lane >> 3;
  const int soff = ((lane & 7) << 4) ^ (srow << 4);

  const int NT = (qb0 + 126) >> 6;

#define STAGE_KV(kbuf, vbuf, j0)                                                      \
  {                                                                                   \
    _Pragma("unroll")                                                                 \
    for (int n = 0; n < 2; ++n) {                                                     \
      int ch = w * 2 + n;                                                             \
      int row = ch * 8 + srow;                                                        \
      GLOAD_LDS16((const char*)(Kh + (size_t)((j0) + row) * HS) + soff,               \
                  &Kt[kbuf][ch * 512]);                                               \
      GLOAD_LDS16((const char*)(Vh + (size_t)row * T_ + (j0)) + soff,                 \
                  &Vt[vbuf][ch * 512]);                                               \
    }                                                                                 \
  }

#define SM_PV(tp)                                                                     \
  {                                                                                   \
    const int j0p = (tp)*64;                                                          \
    const char* Vb = (const char*)&Vt[(tp) % 3][0];                                   \
    _Pragma("unroll")                                                                 \
    for (int nt = 0; nt < 4; ++nt) {                                                  \
      float p[4];                                                                     \
      _Pragma("unroll")                                                               \
      for (int r = 0; r < 4; ++r) {                                                   \
        int j = j0p + nt * 16 + lg * 4 + r;                                           \
        p[r] = (j < tq) ? exp2f(fmaf(sp[nt][r], L2E, -m0l)) : 0.f;                    \
        lsum += p[r];                                                                 \
      }                                                                               \
      unsigned int w0, w1;                                                            \
      asm("v_cvt_pk_bf16_f32 %0, %1, %2" : "=v"(w0) : "v"(p[0]), "v"(p[1]));          \
      asm("v_cvt_pk_bf16_f32 %0, %1, %2" : "=v"(w1) : "v"(p[2]), "v"(p[3]));          \
      uint2 pk; pk.x = w0; pk.y = w1;                                                 \
      *(uint2*)(pb + nt * 32 + lg * 8) = pk;                                          \
    }                                                                                 \
    __builtin_amdgcn_s_setprio(1);                                                    \
    _Pragma("unroll")                                                                 \
    for (int ks = 0; ks < 2; ++ks) {                                                  \
      short8 pf = *(const short8*)(pb + ks * 64 + lg * 16);                           \
      _Pragma("unroll")                                                               \
      for (int mt = 0; mt < 4; ++mt) {                                                \
        short8 vf = *(const short8*)(Vb + (mt * 16 + q16) * 128 +                     \
                                     ((ks * 64 + lg * 16) ^ swr));                    \
        accO[mt] = __builtin_amdgcn_mfma_f32_16x16x32_bf16(vf, pf, accO[mt], 0, 0, 0);\
      }                                                                               \
    }                                                                                 \
    __builtin_amdgcn_s_setprio(0);                                                    \
  }

  STAGE_KV(0, 0, 0);

  for (int kt = 0; kt < NT; ++kt) {
    const int j0 = kt * 64;
    if (kt + 1 < NT) {
      STAGE_KV((kt + 1) & 1, (kt + 1) % 3, j0 + 64);
      asm volatile("s_waitcnt vmcnt(4)" ::: "memory");
    } else {
      asm volatile("s_waitcnt vmcnt(0)" ::: "memory");
    }
    __builtin_amdgcn_s_barrier();
    __builtin_amdgcn_sched_barrier(0);

    const char* Kb = (const char*)&Kt[kt & 1][0];
    short8 kf[4][2];
#pragma unroll
    for (int nt = 0; nt < 4; ++nt)
#pragma unroll
      for (int ks = 0; ks < 2; ++ks)
        kf[nt][ks] = *(const short8*)(Kb + (nt * 16 + q16) * 128 + ((ks * 64 + lg * 16) ^ swr));
    f32x4 sc[4];
    __builtin_amdgcn_s_setprio(1);
#pragma unroll
    for (int nt = 0; nt < 4; ++nt) {
      sc[nt] = __builtin_amdgcn_mfma_f32_16x16x32_bf16(kf[nt][0], qf[0], zero, 0, 0, 0);
      sc[nt] = __builtin_amdgcn_mfma_f32_16x16x32_bf16(kf[nt][1], qf[1], sc[nt], 0, 0, 0);
    }
    __builtin_amdgcn_s_setprio(0);

    if (kt > 0) SM_PV(kt - 1);

#pragma unroll
    for (int nt = 0; nt < 4; ++nt) sp[nt] = sc[nt];

    asm volatile("s_waitcnt lgkmcnt(0)" ::: "memory");
    __builtin_amdgcn_s_barrier();
  }
  SM_PV(NT - 1);

  {
    float v = lsum;
    v += __shfl_xor(v, 16, 64);
    v += __shfl_xor(v, 32, 64);
    float inv = 1.f / v;
    if (tq < T_) {
      unsigned short* yp = Yh + (size_t)tq * C_;
#pragma unroll
      for (int mt = 0; mt < 4; ++mt) {
        float o0 = accO[mt][0] * inv, o1 = accO[mt][1] * inv;
        float o2 = accO[mt][2] * inv, o3 = accO[mt][3] * inv;
        unsigned int u0, u1;
        asm("v_cvt_pk_bf16_f32 %0, %1, %2" : "=v"(u0) : "v"(o0), "v"(o1));
        asm("v_cvt_pk_bf16_f32 %0, %1, %2" : "=v"(u1) : "v"(o2), "v"(o3));
        uint2 pk; pk.x = u0; pk.y = u1;
        *(uint2*)(yp + mt * 16 + lg * 4) = pk;
      }
    }
  }
#undef STAGE_KV
#undef SM_PV
}

extern "C" void kernel_launch(void* const* d_in, const int* in_sizes, int n_in,
                              void* d_out, int out_size, void* d_ws, size_t ws_size,
                              hipStream_t stream) {
  const float* x          = (const float*)d_in[0];
  const float* W_la       = (const float*)d_in[1];
  const float* la_coef    = (const float*)d_in[2];
  const float* W_v        = (const float*)d_in[3];
  const float* v_coef     = (const float*)d_in[4];
  const float* kernel_bet = (const float*)d_in[5];
  const float* value_bet  = (const float*)d_in[6];
  const float* W_proj     = (const float*)d_in[7];
  float* out = (float*)d_out;

  char* ws = (char*)d_ws;
  const size_t NTOK = (size_t)B_ * T_ * C_;            // 3,145,728
  const size_t NSEGTOT = (size_t)B_ * NH * NSEG * HS;  // 98,304
  unsigned short* uxv = (unsigned short*)ws;                       // (B*T, CX) bf16
  float* segend  = (float*)(ws + (size_t)B_ * T_ * CX * 2);
  float* carryin = segend + NSEGTOT;
  __hip_bfloat16* kb16 = (__hip_bfloat16*)(carryin + NSEGTOT);     // (B,NH,T,HS)
  __hip_bfloat16* vt16 = kb16 + NTOK;                              // (B,NH,HS,T)
  __hip_bfloat16* xb   = vt16 + NTOK;                              // (B*T,C) bf16
  __hip_bfloat16* Wcat = xb + NTOK;                                // (1536,768) bf16
  __hip_bfloat16* Wpb  = Wcat + (size_t)CX * C_;                   // (768,768) bf16
  __hip_bfloat16* yb   = xb;  // alias: xb dead after gemm1

  const int M = B_ * T_;

  cast_all<<<2048, 256, 0, stream>>>(x, W_la, W_v, W_proj, xb, Wcat, Wpb);

  // uxv (bf16) = xb @ [W_la; W_v]^T
  gemm_bf16<64, true><<<dim3(M / 64, CX / 128), 256, 0, stream>>>(xb, Wcat, uxv, M, CX, C_);

  scan_seg<<<dim3(B_ * NH * NSEG / 4), 256, 0, stream>>>(uxv, la_coef, segend);
  scan_b<<<dim3((B_ * NH * HS + 255) / 256), 256, 0, stream>>>(la_coef, segend, carryin);
  scanc_vbuild<<<dim3(B_ * NH * NSEG / 4 + 32 * B_ * NH), 256, 0, stream>>>(
      la_coef, kernel_bet, carryin, uxv, v_coef, value_bet, kb16, vt16);

  attn7<<<dim3(B_ * NH, 32), 256, 0, stream>>>(kb16, vt16, kernel_bet, yb);

  gemm_bf16<64, false><<<dim3(M / 64, C_ / 128), 256, 0, stream>>>(yb, Wpb, out, M, C_, C_);
}